// Round 5
// baseline (419.511 us; speedup 1.0000x reference)
//
#include <hip/hip_runtime.h>
#include <hip/hip_bf16.h>
#include <cstdint>

// ---------------------------------------------------------------------------
// BaseAttention: GQA fwd, b=1 S=4096 d=2048, 32 Q / 8 KV heads, HD=64, causal.
// fp32 in/out; bf16 intermediates.
//
// Round 12 (= Round 11 + QBLK 128->256: 64 q-rows per wave, 4 mt sub-tiles):
//  - R11 counters: MfmaUtil 21.7 / VALUBusy 39 with LDS reads ~4x the MFMA
//    cycle cost (each wave reads the whole 8KB K-tile + 8KB V-tile per
//    k-tile). K/V LDS bytes per MFMA halve when each wave owns 64 q-rows.
//  - Grid: 8 pairs x 32 heads = 256 blocks (pair p with 15-p => uniform 68
//    k-tiles per block, 1 block/CU). VGPR budget: launch_bounds(256,2).
//  - Per-tile pipeline unchanged: double-buffered K/V via global_load_lds,
//    swapped QK^T (mfma(K,Q)), word-granular P repack through 8 KiB Pu,
//    acc init -16 folds softmax offset.
//  - Fused QKV projection + out-projection GEMM + casts unchanged.
// ---------------------------------------------------------------------------

typedef unsigned int u32;
typedef unsigned short u16;
typedef __attribute__((ext_vector_type(8))) short bf16x8;
typedef __attribute__((ext_vector_type(4))) float f32x4;
typedef __attribute__((ext_vector_type(2))) u32 u32x2;

typedef __attribute__((address_space(3))) void lds_void_t;
typedef __attribute__((address_space(1))) void gbl_void_t;

__device__ __forceinline__ void gload_lds16(const u16* g, u16* l) {
    __builtin_amdgcn_global_load_lds((const gbl_void_t*)g, (lds_void_t*)l, 16, 0, 0);
}

__device__ __forceinline__ u16 f2bf(float f) {
    union { float f; u32 i; } c; c.f = f;
    return (u16)((c.i + 0x7fffu + ((c.i >> 16) & 1u)) >> 16);
}
__device__ __forceinline__ float bfround(float f) {
    union { float f; u32 i; } c; c.f = f;
    c.i = (c.i + 0x7fffu + ((c.i >> 16) & 1u)) & 0xffff0000u;
    return c.f;
}
__device__ __forceinline__ u32 packbf2(float a, float b) {  // v_cvt_pk_bf16_f32
    union { __hip_bfloat162 h; u32 w; } c;
    c.h = __float22bfloat162_rn(make_float2(a, b));
    return c.w;   // a in low 16, b in high 16
}

// ---------------------------------------------------------------------------
// casts
// ---------------------------------------------------------------------------
__global__ __launch_bounds__(256) void cast_f2b_kernel(
    const float* __restrict__ s, u16* __restrict__ d)
{
    int i = (blockIdx.x * 256 + threadIdx.x) * 8;
    float4 a = *reinterpret_cast<const float4*>(s + i);
    float4 b = *reinterpret_cast<const float4*>(s + i + 4);
    u32 w[4];
    w[0] = packbf2(a.x, a.y); w[1] = packbf2(a.z, a.w);
    w[2] = packbf2(b.x, b.y); w[3] = packbf2(b.z, b.w);
    *reinterpret_cast<uint4*>(d + i) = *reinterpret_cast<const uint4*>(w);
}

__global__ __launch_bounds__(256) void cast_transpose_kernel(
    const float* __restrict__ W, u16* __restrict__ Wt, int K, int N)
{
    __shared__ float tile[64][65];
    const int k0 = blockIdx.y * 64, n0 = blockIdx.x * 64;
    const int t = threadIdx.x;
#pragma unroll
    for (int i = 0; i < 16; ++i) {
        int idx = t + i * 256;
        int r = idx >> 6, c = idx & 63;
        tile[r][c] = W[(size_t)(k0 + r) * N + n0 + c];
    }
    __syncthreads();
#pragma unroll
    for (int i = 0; i < 16; ++i) {
        int idx = t + i * 256;
        int r = idx >> 6, c = idx & 63;
        Wt[(size_t)(n0 + r) * K + k0 + c] = f2bf(tile[c][r]);
    }
}

// ---------------------------------------------------------------------------
// Fused QKV MFMA GEMM. A = xb[4096][2048], Bt = Wqkvt[3072][2048]
// (rows 0..2047 = Wq^T, 2048..2559 = Wk^T, 2560..3071 = Wv^T).
// Column tile routes: Q (bf16, scaled) / K (bf16) / V (bf16 transposed).
// ---------------------------------------------------------------------------
__global__ __launch_bounds__(256) void gemm_qkv_kernel(
    const u16* __restrict__ A, const u16* __restrict__ Bt,
    u16* __restrict__ Qw, u16* __restrict__ Kw, u16* __restrict__ Vtw,
    int M, int K, float qscale)
{
    __shared__ __align__(16) u16 As[128][32];
    __shared__ __align__(16) u16 Bs[128][32];

    const int tid  = threadIdx.x;
    const int wave = tid >> 6;
    const int lane = tid & 63;
    const int col  = lane & 15;
    const int quad = lane >> 4;
    const int bm = blockIdx.y * 128, bn = blockIdx.x * 128;
    const int mhalf = (wave & 1) * 64, nhalf = (wave >> 1) * 64;

    const int srow = wave * 32 + (lane >> 2);
    const int skch = lane & 3;
    const u16* ga = A  + (size_t)(bm + srow) * K + skch * 8;
    const u16* gb = Bt + (size_t)(bn + srow) * K + skch * 8;
    u16* lA0 = &As[wave * 32][0];
    u16* lA1 = &As[wave * 32 + 16][0];
    u16* lB0 = &Bs[wave * 32][0];
    u16* lB1 = &Bs[wave * 32 + 16][0];

    f32x4 acc[4][4];
#pragma unroll
    for (int i = 0; i < 4; ++i)
#pragma unroll
        for (int j = 0; j < 4; ++j) acc[i][j] = (f32x4){0.f, 0.f, 0.f, 0.f};

    for (int k0 = 0; k0 < K; k0 += 32) {
        __syncthreads();
        gload_lds16(ga, lA0);
        gload_lds16(ga + 16 * K, lA1);
        gload_lds16(gb, lB0);
        gload_lds16(gb + 16 * K, lB1);
        ga += 32; gb += 32;
        __syncthreads();

        bf16x8 af[4], bf[4];
#pragma unroll
        for (int t = 0; t < 4; ++t)
            af[t] = *reinterpret_cast<const bf16x8*>(&As[mhalf + t * 16 + col][quad * 8]);
#pragma unroll
        for (int t = 0; t < 4; ++t)
            bf[t] = *reinterpret_cast<const bf16x8*>(&Bs[nhalf + t * 16 + col][quad * 8]);
#pragma unroll
        for (int tm = 0; tm < 4; ++tm)
#pragma unroll
            for (int tn = 0; tn < 4; ++tn)
                acc[tm][tn] = __builtin_amdgcn_mfma_f32_16x16x32_bf16(
                    af[tm], bf[tn], acc[tm][tn], 0, 0, 0);
    }

    if (bn < 2048) {            // ---- Q route (scaled, row-major [M][2048])
#pragma unroll
        for (int tm = 0; tm < 4; ++tm) {
            int row0 = bm + mhalf + tm * 16 + quad * 4;
#pragma unroll
            for (int r = 0; r < 4; ++r) {
                u16* cp = Qw + (size_t)(row0 + r) * 2048 + bn + nhalf + col;
#pragma unroll
                for (int tn = 0; tn < 4; ++tn)
                    cp[tn * 16] = f2bf(acc[tm][tn][r] * qscale);
            }
        }
    } else if (bn < 2560) {     // ---- K route (row-major [M][512])
        const int cb = bn - 2048;
#pragma unroll
        for (int tm = 0; tm < 4; ++tm) {
            int row0 = bm + mhalf + tm * 16 + quad * 4;
#pragma unroll
            for (int r = 0; r < 4; ++r) {
                u16* cp = Kw + (size_t)(row0 + r) * 512 + cb + nhalf + col;
#pragma unroll
                for (int tn = 0; tn < 4; ++tn)
                    cp[tn * 16] = f2bf(acc[tm][tn][r]);
            }
        }
    } else {                    // ---- V route (transposed [512][M])
        const int cb = bn - 2560;
#pragma unroll
        for (int tn = 0; tn < 4; ++tn) {
            int nrow = cb + nhalf + tn * 16 + col;
#pragma unroll
            for (int tm = 0; tm < 4; ++tm) {
                int m0 = bm + mhalf + tm * 16 + quad * 4;
                ushort4 v;
                v.x = f2bf(acc[tm][tn][0]); v.y = f2bf(acc[tm][tn][1]);
                v.z = f2bf(acc[tm][tn][2]); v.w = f2bf(acc[tm][tn][3]);
                *reinterpret_cast<ushort4*>(&Vtw[(size_t)nrow * M + m0]) = v;
            }
        }
    }
}

// ---------------------------------------------------------------------------
// Out-projection MFMA GEMM: fp32 output + bias (bf16-rounded values).
// ---------------------------------------------------------------------------
__global__ __launch_bounds__(256) void gemm_out_kernel(
    const u16* __restrict__ A, const u16* __restrict__ Bt,
    const float* __restrict__ bias, float* __restrict__ Co,
    int M, int N, int K)
{
    __shared__ __align__(16) u16 As[128][32];
    __shared__ __align__(16) u16 Bs[128][32];

    const int tid  = threadIdx.x;
    const int wave = tid >> 6;
    const int lane = tid & 63;
    const int col  = lane & 15;
    const int quad = lane >> 4;
    const int bm = blockIdx.y * 128, bn = blockIdx.x * 128;
    const int mhalf = (wave & 1) * 64, nhalf = (wave >> 1) * 64;

    const int srow = wave * 32 + (lane >> 2);
    const int skch = lane & 3;
    const u16* ga = A  + (size_t)(bm + srow) * K + skch * 8;
    const u16* gb = Bt + (size_t)(bn + srow) * K + skch * 8;
    u16* lA0 = &As[wave * 32][0];
    u16* lA1 = &As[wave * 32 + 16][0];
    u16* lB0 = &Bs[wave * 32][0];
    u16* lB1 = &Bs[wave * 32 + 16][0];

    f32x4 acc[4][4];
#pragma unroll
    for (int i = 0; i < 4; ++i)
#pragma unroll
        for (int j = 0; j < 4; ++j) acc[i][j] = (f32x4){0.f, 0.f, 0.f, 0.f};

    for (int k0 = 0; k0 < K; k0 += 32) {
        __syncthreads();
        gload_lds16(ga, lA0);
        gload_lds16(ga + 16 * K, lA1);
        gload_lds16(gb, lB0);
        gload_lds16(gb + 16 * K, lB1);
        ga += 32; gb += 32;
        __syncthreads();

        bf16x8 af[4], bf[4];
#pragma unroll
        for (int t = 0; t < 4; ++t)
            af[t] = *reinterpret_cast<const bf16x8*>(&As[mhalf + t * 16 + col][quad * 8]);
#pragma unroll
        for (int t = 0; t < 4; ++t)
            bf[t] = *reinterpret_cast<const bf16x8*>(&Bs[nhalf + t * 16 + col][quad * 8]);
#pragma unroll
        for (int tm = 0; tm < 4; ++tm)
#pragma unroll
            for (int tn = 0; tn < 4; ++tn)
                acc[tm][tn] = __builtin_amdgcn_mfma_f32_16x16x32_bf16(
                    af[tm], bf[tn], acc[tm][tn], 0, 0, 0);
    }

    float bj[4];
#pragma unroll
    for (int tn = 0; tn < 4; ++tn) bj[tn] = bias[bn + nhalf + tn * 16 + col];
#pragma unroll
    for (int tm = 0; tm < 4; ++tm) {
        int row0 = bm + mhalf + tm * 16 + quad * 4;
#pragma unroll
        for (int r = 0; r < 4; ++r) {
            float* cp = Co + (size_t)(row0 + r) * N + bn + nhalf + col;
#pragma unroll
            for (int tn = 0; tn < 4; ++tn)
                cp[tn * 16] = bfround(acc[tm][tn][r] + bj[tn]);
        }
    }
}

// ---------------------------------------------------------------------------
// Flash attention, fixed-offset softmax, double-buffered K/V staging,
// SWAPPED QK^T (mfma(K,Q)): D[key][qrow]; acc init -16 folds softmax offset.
// P repack via Pu (see R10 header). QBLK=256: 4 waves x 64 q-rows (4 mt).
// Causal load balance: block = q-tile pair (15-p heavy pass, then p);
// 68 k-tiles/block, uniform; grid 8x32 = 256 blocks = 1/CU.
// ---------------------------------------------------------------------------
__global__ __launch_bounds__(256, 2) void attn_mfma_kernel(
    const u16* __restrict__ Q,
    const u16* __restrict__ Kd,
    const u16* __restrict__ Vt,
    u16* __restrict__ CTX,
    int S)
{
    __shared__ __align__(16) u16 Ks[2][64][64];
    __shared__ __align__(16) u16 Vs[2][64][64];
    __shared__ __align__(16) u32 Pu[4][512];

    const int pairi = blockIdx.x;          // 0..7
    const int h    = blockIdx.y;
    const int g    = h >> 2;
    const int tid  = threadIdx.x;
    const int wave = tid >> 6;
    const int lane = tid & 63;
    const int col  = lane & 15;
    const int quad = lane >> 4;

    const int srow8 = lane >> 3;
    const int schk  = (lane & 7) ^ srow8;
    const u16* gK = Kd + (size_t)(wave * 16 + srow8) * 512 + g * 64 + schk * 8;
    const u16* gV = Vt + (size_t)(g * 64 + wave * 16 + srow8) * 4096 + schk * 8;

    // Pu word index for packed-P writes (per t: +128 words)
    const int wbase = ((quad >> 1) * 16 + col) * 4 + (quad & 1) * 2;

#pragma unroll 1
    for (int pass = 0; pass < 2; ++pass) {
        const int qt = pass ? pairi : (15 - pairi);   // heavy pass first
        const int qb = qt * 256;

        bf16x8 qf[4][2];
#pragma unroll
        for (int mt = 0; mt < 4; ++mt) {
            const u16* qp = Q + (size_t)(qb + wave * 64 + mt * 16 + col) * 2048
                            + h * 64 + quad * 8;
            qf[mt][0] = *reinterpret_cast<const bf16x8*>(qp);
            qf[mt][1] = *reinterpret_cast<const bf16x8*>(qp + 32);
        }

        f32x4 o_acc[4][4];
        float l_acc[4];
#pragma unroll
        for (int mt = 0; mt < 4; ++mt) {
            l_acc[mt] = 0.f;
#pragma unroll
            for (int t = 0; t < 4; ++t)
                o_acc[mt][t] = (f32x4){0.f, 0.f, 0.f, 0.f};
        }

        const int ktmax = 4 * qt + 3;

        // prefetch tile 0 into buffer 0
        gload_lds16(gK, &Ks[0][wave * 16][0]);
        gload_lds16(gK + (size_t)8 * 512, &Ks[0][wave * 16 + 8][0]);
        gload_lds16(gV, &Vs[0][wave * 16][0]);
        gload_lds16(gV + 8 * 4096, &Vs[0][wave * 16 + 8][0]);

        for (int kt = 0; kt <= ktmax; ++kt) {
            const int kbase = kt * 64;
            const int cur = kt & 1;
            __syncthreads();   // drains DMA into buf[cur]; fences buf[cur^1] reuse

            if (kt < ktmax) {  // prefetch kt+1 into the other buffer
                const int nb = cur ^ 1;
                const size_t ko = (size_t)(kbase + 64);
                gload_lds16(gK + ko * 512, &Ks[nb][wave * 16][0]);
                gload_lds16(gK + (ko + 8) * 512, &Ks[nb][wave * 16 + 8][0]);
                gload_lds16(gV + ko, &Vs[nb][wave * 16][0]);
                gload_lds16(gV + 8 * 4096 + ko, &Vs[nb][wave * 16 + 8][0]);
            }

#pragma unroll
            for (int mt = 0; mt < 4; ++mt) {
                const int minrow = qb + wave * 64 + mt * 16;
                if (kbase > minrow + 15) continue;             // fully masked
                const int qrow = minrow + col;

                // ---- S^T = K Q^T (swapped): D[key][qrow], acc init -16 ----
                f32x4 sc[4];
#pragma unroll
                for (int t = 0; t < 4; ++t) {
                    const int krow = t * 16 + col;
                    bf16x8 k0 = *reinterpret_cast<const bf16x8*>(
                        &Ks[cur][krow][((quad    ) ^ (krow & 7)) * 8]);
                    bf16x8 k1 = *reinterpret_cast<const bf16x8*>(
                        &Ks[cur][krow][((quad + 4) ^ (krow & 7)) * 8]);
                    f32x4 c4 = {-16.f, -16.f, -16.f, -16.f};
                    c4 = __builtin_amdgcn_mfma_f32_16x16x32_bf16(k0, qf[mt][0], c4, 0, 0, 0);
                    c4 = __builtin_amdgcn_mfma_f32_16x16x32_bf16(k1, qf[mt][1], c4, 0, 0, 0);
                    sc[t] = c4;
                }
                if (kbase + 63 > minrow) {                     // causal mask
#pragma unroll
                    for (int t = 0; t < 4; ++t) {
                        const int keyq = kbase + t * 16 + quad * 4;
#pragma unroll
                        for (int r = 0; r < 4; ++r)
                            if (keyq + r > qrow) sc[t][r] = -1e30f;
                    }
                }

                // ---- p = exp2(sc); pack into PV A-fragment words ----
                float lsum = 0.f;
#pragma unroll
                for (int t = 0; t < 4; ++t) {
                    float p0 = __builtin_amdgcn_exp2f(sc[t][0]);
                    float p1 = __builtin_amdgcn_exp2f(sc[t][1]);
                    float p2 = __builtin_amdgcn_exp2f(sc[t][2]);
                    float p3 = __builtin_amdgcn_exp2f(sc[t][3]);
                    lsum += (p0 + p1) + (p2 + p3);
                    u32x2 w;
                    w.x = packbf2(p0, p1);
                    w.y = packbf2(p2, p3);
                    *reinterpret_cast<u32x2*>(&Pu[wave][wbase + t * 128]) = w;
                }
                l_acc[mt] += lsum;

                // drain LDS writes only (lgkmcnt(0); vmcnt=63 keeps DMA in flight)
                __builtin_amdgcn_s_waitcnt(0xC07F);
                __builtin_amdgcn_wave_barrier();

                bf16x8 pa0 = *reinterpret_cast<const bf16x8*>(&Pu[wave][lane * 4]);
                bf16x8 pa1 = *reinterpret_cast<const bf16x8*>(&Pu[wave][256 + lane * 4]);

                // ---- O += P V ----
#pragma unroll
                for (int t = 0; t < 4; ++t) {
                    const int d = t * 16 + col;
                    bf16x8 vb0 = *reinterpret_cast<const bf16x8*>(
                        &Vs[cur][d][((quad    ) ^ (d & 7)) * 8]);
                    bf16x8 vb1 = *reinterpret_cast<const bf16x8*>(
                        &Vs[cur][d][((quad + 4) ^ (d & 7)) * 8]);
                    o_acc[mt][t] = __builtin_amdgcn_mfma_f32_16x16x32_bf16(pa0, vb0, o_acc[mt][t], 0, 0, 0);
                    o_acc[mt][t] = __builtin_amdgcn_mfma_f32_16x16x32_bf16(pa1, vb1, o_acc[mt][t], 0, 0, 0);
                }
            }
        }

        // ---- epilogue (per pass) ----
#pragma unroll
        for (int mt = 0; mt < 4; ++mt) {
            // full row-sum for qrow=col lives split across quads: reduce
            float v = l_acc[mt];
            v += __shfl_xor(v, 16, 64);
            v += __shfl_xor(v, 32, 64);
            // redistribute: lane needs l for qrow = quad*4 + r (o_acc row layout)
            const int src0 = (lane & 48) + ((lane >> 4) & 3) * 4;
#pragma unroll
            for (int r = 0; r < 4; ++r) {
                const float lv = __shfl(v, src0 + r, 64);
                const float inv = 1.f / lv;
                const int row = qb + wave * 64 + mt * 16 + quad * 4 + r;
                u16* cp = CTX + (size_t)row * 2048 + h * 64;
#pragma unroll
                for (int t = 0; t < 4; ++t)
                    cp[t * 16 + col] = f2bf(o_acc[mt][t][r] * inv);
            }
        }
    }
}

// ---------------------------------------------------------------------------
extern "C" void kernel_launch(void* const* d_in, const int* in_sizes, int n_in,
                              void* d_out, int out_size, void* d_ws, size_t ws_size,
                              hipStream_t stream)
{
    const float* x  = (const float*)d_in[0];   // [4096, 2048]
    const float* Wq = (const float*)d_in[1];   // [2048, 2048]
    const float* Wk = (const float*)d_in[2];   // [2048, 512]
    const float* Wv = (const float*)d_in[3];   // [2048, 512]
    const float* Wo = (const float*)d_in[4];   // [2048, 2048]
    const float* bo = (const float*)d_in[5];   // [2048]
    float* out = (float*)d_out;                // [4096, 2048]

    const int S = 4096, Din = 2048, Dq = 2048, Dkv = 512;
    const float QSCALE = 0.125f * 1.44269504f; // 1/sqrt(64) * log2(e)

    u16* xb  = (u16*)d_ws;                    // [4096][2048]
    u16* Qw  = xb + (size_t)S * Din;          // [4096][2048]
    u16* Kw  = Qw + (size_t)S * Dq;           // [4096][512]
    u16* Vtw = Kw + (size_t)S * Dkv;          // [512][4096]
    u16* Cw   = xb;        // CTX aliases xb (dead after QKV proj)
    u16* Wobt = Qw;        // Wo^T aliases Q (dead after attn)

    // d_out as scratch: fused Wqkv^T bf16 [3072][2048] (12.6 MB <= 33.5 MB)
    u16* Wqkvt = (u16*)d_out;

    dim3 blk(256);
    cast_f2b_kernel<<<dim3((S * Din) / (256 * 8)), blk, 0, stream>>>(x, xb);
    cast_transpose_kernel<<<dim3(Dq  / 64, Din / 64), blk, 0, stream>>>(Wq, Wqkvt, Din, Dq);
    cast_transpose_kernel<<<dim3(Dkv / 64, Din / 64), blk, 0, stream>>>(Wk, Wqkvt + (size_t)2048 * Din, Din, Dkv);
    cast_transpose_kernel<<<dim3(Dkv / 64, Din / 64), blk, 0, stream>>>(Wv, Wqkvt + (size_t)2560 * Din, Din, Dkv);

    gemm_qkv_kernel<<<dim3(3072 / 128, S / 128), blk, 0, stream>>>(
        xb, Wqkvt, Qw, Kw, Vtw, S, Din, QSCALE);

    attn_mfma_kernel<<<dim3(8, 32), blk, 0, stream>>>(Qw, Kw, Vtw, Cw, S);

    cast_transpose_kernel<<<dim3(Dq / 64, Dq / 64), blk, 0, stream>>>(Wo, Wobt, Dq, Dq);
    gemm_out_kernel<<<dim3(Dq / 128, S / 128), blk, 0, stream>>>(Cw, Wobt, bo, out, S, Dq, Dq);
}

// Round 6
// 364.531 us; speedup vs baseline: 1.1508x; 1.1508x over previous
//
#include <hip/hip_runtime.h>
#include <hip/hip_bf16.h>
#include <cstdint>

// ---------------------------------------------------------------------------
// BaseAttention: GQA fwd, b=1 S=4096 d=2048, 32 Q / 8 KV heads, HD=64, causal.
// fp32 in/out; bf16 intermediates.
//
// Round 13 (= Round 11 residency + K/V LDS reads shared across mt):
//  - R12 post-mortem: K/V fragment reads were INSIDE the mt loop, so more
//    q-rows/wave never cut LDS bytes per MFMA; and 1 block/CU lost barrier
//    hiding (132->183us). Reverted to QBLK=128, grid 16x32, 2 blocks/CU.
//  - New: t is the outer loop in both QK and PV phases; each K/V fragment
//    is read from LDS ONCE and feeds both mt MFMAs. Per-wave b128 reads
//    per k-tile: 36 -> 20. Pu doubled to [4][1024] (both mt's P live),
//    single lgkm drain per tile. LDS 48 KiB (still 2 blocks/CU).
//  - Per-tile pipeline otherwise unchanged: double-buffered K/V staging
//    via global_load_lds, swapped QK^T (mfma(K,Q)), word-granular P repack,
//    acc init -16 folds softmax offset. Pair (31-p, p): 66 tiles/block.
//  - Fused QKV projection + out-projection GEMM + casts unchanged.
// ---------------------------------------------------------------------------

typedef unsigned int u32;
typedef unsigned short u16;
typedef __attribute__((ext_vector_type(8))) short bf16x8;
typedef __attribute__((ext_vector_type(4))) float f32x4;
typedef __attribute__((ext_vector_type(2))) u32 u32x2;

typedef __attribute__((address_space(3))) void lds_void_t;
typedef __attribute__((address_space(1))) void gbl_void_t;

__device__ __forceinline__ void gload_lds16(const u16* g, u16* l) {
    __builtin_amdgcn_global_load_lds((const gbl_void_t*)g, (lds_void_t*)l, 16, 0, 0);
}

__device__ __forceinline__ u16 f2bf(float f) {
    union { float f; u32 i; } c; c.f = f;
    return (u16)((c.i + 0x7fffu + ((c.i >> 16) & 1u)) >> 16);
}
__device__ __forceinline__ float bfround(float f) {
    union { float f; u32 i; } c; c.f = f;
    c.i = (c.i + 0x7fffu + ((c.i >> 16) & 1u)) & 0xffff0000u;
    return c.f;
}
__device__ __forceinline__ u32 packbf2(float a, float b) {  // v_cvt_pk_bf16_f32
    union { __hip_bfloat162 h; u32 w; } c;
    c.h = __float22bfloat162_rn(make_float2(a, b));
    return c.w;   // a in low 16, b in high 16
}

// ---------------------------------------------------------------------------
// casts
// ---------------------------------------------------------------------------
__global__ __launch_bounds__(256) void cast_f2b_kernel(
    const float* __restrict__ s, u16* __restrict__ d)
{
    int i = (blockIdx.x * 256 + threadIdx.x) * 8;
    float4 a = *reinterpret_cast<const float4*>(s + i);
    float4 b = *reinterpret_cast<const float4*>(s + i + 4);
    u32 w[4];
    w[0] = packbf2(a.x, a.y); w[1] = packbf2(a.z, a.w);
    w[2] = packbf2(b.x, b.y); w[3] = packbf2(b.z, b.w);
    *reinterpret_cast<uint4*>(d + i) = *reinterpret_cast<const uint4*>(w);
}

__global__ __launch_bounds__(256) void cast_transpose_kernel(
    const float* __restrict__ W, u16* __restrict__ Wt, int K, int N)
{
    __shared__ float tile[64][65];
    const int k0 = blockIdx.y * 64, n0 = blockIdx.x * 64;
    const int t = threadIdx.x;
#pragma unroll
    for (int i = 0; i < 16; ++i) {
        int idx = t + i * 256;
        int r = idx >> 6, c = idx & 63;
        tile[r][c] = W[(size_t)(k0 + r) * N + n0 + c];
    }
    __syncthreads();
#pragma unroll
    for (int i = 0; i < 16; ++i) {
        int idx = t + i * 256;
        int r = idx >> 6, c = idx & 63;
        Wt[(size_t)(n0 + r) * K + k0 + c] = f2bf(tile[c][r]);
    }
}

// ---------------------------------------------------------------------------
// Fused QKV MFMA GEMM. A = xb[4096][2048], Bt = Wqkvt[3072][2048]
// (rows 0..2047 = Wq^T, 2048..2559 = Wk^T, 2560..3071 = Wv^T).
// Column tile routes: Q (bf16, scaled) / K (bf16) / V (bf16 transposed).
// ---------------------------------------------------------------------------
__global__ __launch_bounds__(256) void gemm_qkv_kernel(
    const u16* __restrict__ A, const u16* __restrict__ Bt,
    u16* __restrict__ Qw, u16* __restrict__ Kw, u16* __restrict__ Vtw,
    int M, int K, float qscale)
{
    __shared__ __align__(16) u16 As[128][32];
    __shared__ __align__(16) u16 Bs[128][32];

    const int tid  = threadIdx.x;
    const int wave = tid >> 6;
    const int lane = tid & 63;
    const int col  = lane & 15;
    const int quad = lane >> 4;
    const int bm = blockIdx.y * 128, bn = blockIdx.x * 128;
    const int mhalf = (wave & 1) * 64, nhalf = (wave >> 1) * 64;

    const int srow = wave * 32 + (lane >> 2);
    const int skch = lane & 3;
    const u16* ga = A  + (size_t)(bm + srow) * K + skch * 8;
    const u16* gb = Bt + (size_t)(bn + srow) * K + skch * 8;
    u16* lA0 = &As[wave * 32][0];
    u16* lA1 = &As[wave * 32 + 16][0];
    u16* lB0 = &Bs[wave * 32][0];
    u16* lB1 = &Bs[wave * 32 + 16][0];

    f32x4 acc[4][4];
#pragma unroll
    for (int i = 0; i < 4; ++i)
#pragma unroll
        for (int j = 0; j < 4; ++j) acc[i][j] = (f32x4){0.f, 0.f, 0.f, 0.f};

    for (int k0 = 0; k0 < K; k0 += 32) {
        __syncthreads();
        gload_lds16(ga, lA0);
        gload_lds16(ga + 16 * K, lA1);
        gload_lds16(gb, lB0);
        gload_lds16(gb + 16 * K, lB1);
        ga += 32; gb += 32;
        __syncthreads();

        bf16x8 af[4], bf[4];
#pragma unroll
        for (int t = 0; t < 4; ++t)
            af[t] = *reinterpret_cast<const bf16x8*>(&As[mhalf + t * 16 + col][quad * 8]);
#pragma unroll
        for (int t = 0; t < 4; ++t)
            bf[t] = *reinterpret_cast<const bf16x8*>(&Bs[nhalf + t * 16 + col][quad * 8]);
#pragma unroll
        for (int tm = 0; tm < 4; ++tm)
#pragma unroll
            for (int tn = 0; tn < 4; ++tn)
                acc[tm][tn] = __builtin_amdgcn_mfma_f32_16x16x32_bf16(
                    af[tm], bf[tn], acc[tm][tn], 0, 0, 0);
    }

    if (bn < 2048) {            // ---- Q route (scaled, row-major [M][2048])
#pragma unroll
        for (int tm = 0; tm < 4; ++tm) {
            int row0 = bm + mhalf + tm * 16 + quad * 4;
#pragma unroll
            for (int r = 0; r < 4; ++r) {
                u16* cp = Qw + (size_t)(row0 + r) * 2048 + bn + nhalf + col;
#pragma unroll
                for (int tn = 0; tn < 4; ++tn)
                    cp[tn * 16] = f2bf(acc[tm][tn][r] * qscale);
            }
        }
    } else if (bn < 2560) {     // ---- K route (row-major [M][512])
        const int cb = bn - 2048;
#pragma unroll
        for (int tm = 0; tm < 4; ++tm) {
            int row0 = bm + mhalf + tm * 16 + quad * 4;
#pragma unroll
            for (int r = 0; r < 4; ++r) {
                u16* cp = Kw + (size_t)(row0 + r) * 512 + cb + nhalf + col;
#pragma unroll
                for (int tn = 0; tn < 4; ++tn)
                    cp[tn * 16] = f2bf(acc[tm][tn][r]);
            }
        }
    } else {                    // ---- V route (transposed [512][M])
        const int cb = bn - 2560;
#pragma unroll
        for (int tn = 0; tn < 4; ++tn) {
            int nrow = cb + nhalf + tn * 16 + col;
#pragma unroll
            for (int tm = 0; tm < 4; ++tm) {
                int m0 = bm + mhalf + tm * 16 + quad * 4;
                ushort4 v;
                v.x = f2bf(acc[tm][tn][0]); v.y = f2bf(acc[tm][tn][1]);
                v.z = f2bf(acc[tm][tn][2]); v.w = f2bf(acc[tm][tn][3]);
                *reinterpret_cast<ushort4*>(&Vtw[(size_t)nrow * M + m0]) = v;
            }
        }
    }
}

// ---------------------------------------------------------------------------
// Out-projection MFMA GEMM: fp32 output + bias (bf16-rounded values).
// ---------------------------------------------------------------------------
__global__ __launch_bounds__(256) void gemm_out_kernel(
    const u16* __restrict__ A, const u16* __restrict__ Bt,
    const float* __restrict__ bias, float* __restrict__ Co,
    int M, int N, int K)
{
    __shared__ __align__(16) u16 As[128][32];
    __shared__ __align__(16) u16 Bs[128][32];

    const int tid  = threadIdx.x;
    const int wave = tid >> 6;
    const int lane = tid & 63;
    const int col  = lane & 15;
    const int quad = lane >> 4;
    const int bm = blockIdx.y * 128, bn = blockIdx.x * 128;
    const int mhalf = (wave & 1) * 64, nhalf = (wave >> 1) * 64;

    const int srow = wave * 32 + (lane >> 2);
    const int skch = lane & 3;
    const u16* ga = A  + (size_t)(bm + srow) * K + skch * 8;
    const u16* gb = Bt + (size_t)(bn + srow) * K + skch * 8;
    u16* lA0 = &As[wave * 32][0];
    u16* lA1 = &As[wave * 32 + 16][0];
    u16* lB0 = &Bs[wave * 32][0];
    u16* lB1 = &Bs[wave * 32 + 16][0];

    f32x4 acc[4][4];
#pragma unroll
    for (int i = 0; i < 4; ++i)
#pragma unroll
        for (int j = 0; j < 4; ++j) acc[i][j] = (f32x4){0.f, 0.f, 0.f, 0.f};

    for (int k0 = 0; k0 < K; k0 += 32) {
        __syncthreads();
        gload_lds16(ga, lA0);
        gload_lds16(ga + 16 * K, lA1);
        gload_lds16(gb, lB0);
        gload_lds16(gb + 16 * K, lB1);
        ga += 32; gb += 32;
        __syncthreads();

        bf16x8 af[4], bf[4];
#pragma unroll
        for (int t = 0; t < 4; ++t)
            af[t] = *reinterpret_cast<const bf16x8*>(&As[mhalf + t * 16 + col][quad * 8]);
#pragma unroll
        for (int t = 0; t < 4; ++t)
            bf[t] = *reinterpret_cast<const bf16x8*>(&Bs[nhalf + t * 16 + col][quad * 8]);
#pragma unroll
        for (int tm = 0; tm < 4; ++tm)
#pragma unroll
            for (int tn = 0; tn < 4; ++tn)
                acc[tm][tn] = __builtin_amdgcn_mfma_f32_16x16x32_bf16(
                    af[tm], bf[tn], acc[tm][tn], 0, 0, 0);
    }

    float bj[4];
#pragma unroll
    for (int tn = 0; tn < 4; ++tn) bj[tn] = bias[bn + nhalf + tn * 16 + col];
#pragma unroll
    for (int tm = 0; tm < 4; ++tm) {
        int row0 = bm + mhalf + tm * 16 + quad * 4;
#pragma unroll
        for (int r = 0; r < 4; ++r) {
            float* cp = Co + (size_t)(row0 + r) * N + bn + nhalf + col;
#pragma unroll
            for (int tn = 0; tn < 4; ++tn)
                cp[tn * 16] = bfround(acc[tm][tn][r] + bj[tn]);
        }
    }
}

// ---------------------------------------------------------------------------
// Flash attention, fixed-offset softmax, double-buffered K/V staging,
// SWAPPED QK^T (mfma(K,Q)): D[key][qrow]; acc init -16 folds softmax offset.
// t-outer phases: each K/V fragment read once from LDS feeds both mt MFMAs.
// Pu[4][1024]: both mt's packed P live; single lgkm drain per k-tile.
// Causal balance: block = q-tile pair (31-p heavy, then p): 66 tiles/block.
// ---------------------------------------------------------------------------
__global__ __launch_bounds__(256, 2) void attn_mfma_kernel(
    const u16* __restrict__ Q,
    const u16* __restrict__ Kd,
    const u16* __restrict__ Vt,
    u16* __restrict__ CTX,
    int S)
{
    __shared__ __align__(16) u16 Ks[2][64][64];
    __shared__ __align__(16) u16 Vs[2][64][64];
    __shared__ __align__(16) u32 Pu[4][1024];

    const int pairi = blockIdx.x;          // 0..15
    const int h    = blockIdx.y;
    const int g    = h >> 2;
    const int tid  = threadIdx.x;
    const int wave = tid >> 6;
    const int lane = tid & 63;
    const int col  = lane & 15;
    const int quad = lane >> 4;

    const int srow8 = lane >> 3;
    const int schk  = (lane & 7) ^ srow8;
    const u16* gK = Kd + (size_t)(wave * 16 + srow8) * 512 + g * 64 + schk * 8;
    const u16* gV = Vt + (size_t)(g * 64 + wave * 16 + srow8) * 4096 + schk * 8;

    // Pu word index for packed-P writes (per t: +128 words; per mt: +512)
    const int wbase = ((quad >> 1) * 16 + col) * 4 + (quad & 1) * 2;

#pragma unroll 1
    for (int pass = 0; pass < 2; ++pass) {
        const int qt = pass ? pairi : (31 - pairi);   // heavy pass first
        const int qb = qt * 128;

        bf16x8 qf[2][2];
#pragma unroll
        for (int mt = 0; mt < 2; ++mt) {
            const u16* qp = Q + (size_t)(qb + wave * 32 + mt * 16 + col) * 2048
                            + h * 64 + quad * 8;
            qf[mt][0] = *reinterpret_cast<const bf16x8*>(qp);
            qf[mt][1] = *reinterpret_cast<const bf16x8*>(qp + 32);
        }

        f32x4 o_acc[2][4];
        float l_acc[2];
#pragma unroll
        for (int mt = 0; mt < 2; ++mt) {
            l_acc[mt] = 0.f;
#pragma unroll
            for (int t = 0; t < 4; ++t)
                o_acc[mt][t] = (f32x4){0.f, 0.f, 0.f, 0.f};
        }

        const int ktmax = 2 * qt + 1;

        // prefetch tile 0 into buffer 0
        gload_lds16(gK, &Ks[0][wave * 16][0]);
        gload_lds16(gK + (size_t)8 * 512, &Ks[0][wave * 16 + 8][0]);
        gload_lds16(gV, &Vs[0][wave * 16][0]);
        gload_lds16(gV + 8 * 4096, &Vs[0][wave * 16 + 8][0]);

        for (int kt = 0; kt <= ktmax; ++kt) {
            const int kbase = kt * 64;
            const int cur = kt & 1;
            __syncthreads();   // drains DMA into buf[cur]; fences buf[cur^1] reuse

            if (kt < ktmax) {  // prefetch kt+1 into the other buffer
                const int nb = cur ^ 1;
                const size_t ko = (size_t)(kbase + 64);
                gload_lds16(gK + ko * 512, &Ks[nb][wave * 16][0]);
                gload_lds16(gK + (ko + 8) * 512, &Ks[nb][wave * 16 + 8][0]);
                gload_lds16(gV + ko, &Vs[nb][wave * 16][0]);
                gload_lds16(gV + 8 * 4096 + ko, &Vs[nb][wave * 16 + 8][0]);
            }

            const int base0 = qb + wave * 32;       // mt=0 row base
            if (kbase > base0 + 31) continue;       // whole tile masked (wave-uniform)
            const bool act0 = (kbase <= base0 + 15);  // mt=0 active this tile

            // ---- QK phase (t outer; K frags read once, feed both mt) ----
            f32x4 sc0[4], sc1[4];
#pragma unroll
            for (int t = 0; t < 4; ++t) {
                const int krow = t * 16 + col;
                bf16x8 k0 = *reinterpret_cast<const bf16x8*>(
                    &Ks[cur][krow][((quad    ) ^ (krow & 7)) * 8]);
                bf16x8 k1 = *reinterpret_cast<const bf16x8*>(
                    &Ks[cur][krow][((quad + 4) ^ (krow & 7)) * 8]);
                f32x4 c4 = {-16.f, -16.f, -16.f, -16.f};
                c4 = __builtin_amdgcn_mfma_f32_16x16x32_bf16(k0, qf[1][0], c4, 0, 0, 0);
                c4 = __builtin_amdgcn_mfma_f32_16x16x32_bf16(k1, qf[1][1], c4, 0, 0, 0);
                sc1[t] = c4;
                if (act0) {
                    f32x4 d4 = {-16.f, -16.f, -16.f, -16.f};
                    d4 = __builtin_amdgcn_mfma_f32_16x16x32_bf16(k0, qf[0][0], d4, 0, 0, 0);
                    d4 = __builtin_amdgcn_mfma_f32_16x16x32_bf16(k1, qf[0][1], d4, 0, 0, 0);
                    sc0[t] = d4;
                }
            }

            // ---- causal mask (qrow(mt) = base0 + mt*16 + col) ----
            if (kbase + 63 > base0) {
#pragma unroll
                for (int t = 0; t < 4; ++t) {
                    const int keyq = kbase + t * 16 + quad * 4;
#pragma unroll
                    for (int r = 0; r < 4; ++r) {
                        if (keyq + r > base0 + 16 + col) sc1[t][r] = -1e30f;
                        if (act0 && (keyq + r > base0 + col)) sc0[t][r] = -1e30f;
                    }
                }
            }

            // ---- p = exp2(sc); pack both mt into PV A-fragment words ----
            {
                float ls0 = 0.f, ls1 = 0.f;
#pragma unroll
                for (int t = 0; t < 4; ++t) {
                    float p0 = __builtin_amdgcn_exp2f(sc1[t][0]);
                    float p1 = __builtin_amdgcn_exp2f(sc1[t][1]);
                    float p2 = __builtin_amdgcn_exp2f(sc1[t][2]);
                    float p3 = __builtin_amdgcn_exp2f(sc1[t][3]);
                    ls1 += (p0 + p1) + (p2 + p3);
                    u32x2 w;
                    w.x = packbf2(p0, p1);
                    w.y = packbf2(p2, p3);
                    *reinterpret_cast<u32x2*>(&Pu[wave][512 + wbase + t * 128]) = w;
                    if (act0) {
                        float q0 = __builtin_amdgcn_exp2f(sc0[t][0]);
                        float q1 = __builtin_amdgcn_exp2f(sc0[t][1]);
                        float q2 = __builtin_amdgcn_exp2f(sc0[t][2]);
                        float q3 = __builtin_amdgcn_exp2f(sc0[t][3]);
                        ls0 += (q0 + q1) + (q2 + q3);
                        u32x2 v;
                        v.x = packbf2(q0, q1);
                        v.y = packbf2(q2, q3);
                        *reinterpret_cast<u32x2*>(&Pu[wave][wbase + t * 128]) = v;
                    }
                }
                l_acc[1] += ls1;
                if (act0) l_acc[0] += ls0;
            }

            // single drain of LDS writes (lgkmcnt(0); vmcnt=63 keeps DMA going)
            __builtin_amdgcn_s_waitcnt(0xC07F);
            __builtin_amdgcn_wave_barrier();

            bf16x8 pa1_0 = *reinterpret_cast<const bf16x8*>(&Pu[wave][512 + lane * 4]);
            bf16x8 pa1_1 = *reinterpret_cast<const bf16x8*>(&Pu[wave][768 + lane * 4]);
            bf16x8 pa0_0, pa0_1;
            if (act0) {
                pa0_0 = *reinterpret_cast<const bf16x8*>(&Pu[wave][lane * 4]);
                pa0_1 = *reinterpret_cast<const bf16x8*>(&Pu[wave][256 + lane * 4]);
            }

            // ---- PV phase (t outer; V frags read once, feed both mt) ----
#pragma unroll
            for (int t = 0; t < 4; ++t) {
                const int d = t * 16 + col;
                bf16x8 vb0 = *reinterpret_cast<const bf16x8*>(
                    &Vs[cur][d][((quad    ) ^ (d & 7)) * 8]);
                bf16x8 vb1 = *reinterpret_cast<const bf16x8*>(
                    &Vs[cur][d][((quad + 4) ^ (d & 7)) * 8]);
                o_acc[1][t] = __builtin_amdgcn_mfma_f32_16x16x32_bf16(pa1_0, vb0, o_acc[1][t], 0, 0, 0);
                o_acc[1][t] = __builtin_amdgcn_mfma_f32_16x16x32_bf16(pa1_1, vb1, o_acc[1][t], 0, 0, 0);
                if (act0) {
                    o_acc[0][t] = __builtin_amdgcn_mfma_f32_16x16x32_bf16(pa0_0, vb0, o_acc[0][t], 0, 0, 0);
                    o_acc[0][t] = __builtin_amdgcn_mfma_f32_16x16x32_bf16(pa0_1, vb1, o_acc[0][t], 0, 0, 0);
                }
            }
        }

        // ---- epilogue (per pass) ----
#pragma unroll
        for (int mt = 0; mt < 2; ++mt) {
            // full row-sum for qrow=col lives split across quads: reduce
            float v = l_acc[mt];
            v += __shfl_xor(v, 16, 64);
            v += __shfl_xor(v, 32, 64);
            // redistribute: lane needs l for qrow = quad*4 + r (o_acc row layout)
            const int src0 = (lane & 48) + ((lane >> 4) & 3) * 4;
#pragma unroll
            for (int r = 0; r < 4; ++r) {
                const float lv = __shfl(v, src0 + r, 64);
                const float inv = 1.f / lv;
                const int row = qb + wave * 32 + mt * 16 + quad * 4 + r;
                u16* cp = CTX + (size_t)row * 2048 + h * 64;
#pragma unroll
                for (int t = 0; t < 4; ++t)
                    cp[t * 16 + col] = f2bf(o_acc[mt][t][r] * inv);
            }
        }
    }
}

// ---------------------------------------------------------------------------
extern "C" void kernel_launch(void* const* d_in, const int* in_sizes, int n_in,
                              void* d_out, int out_size, void* d_ws, size_t ws_size,
                              hipStream_t stream)
{
    const float* x  = (const float*)d_in[0];   // [4096, 2048]
    const float* Wq = (const float*)d_in[1];   // [2048, 2048]
    const float* Wk = (const float*)d_in[2];   // [2048, 512]
    const float* Wv = (const float*)d_in[3];   // [2048, 512]
    const float* Wo = (const float*)d_in[4];   // [2048, 2048]
    const float* bo = (const float*)d_in[5];   // [2048]
    float* out = (float*)d_out;                // [4096, 2048]

    const int S = 4096, Din = 2048, Dq = 2048, Dkv = 512;
    const float QSCALE = 0.125f * 1.44269504f; // 1/sqrt(64) * log2(e)

    u16* xb  = (u16*)d_ws;                    // [4096][2048]
    u16* Qw  = xb + (size_t)S * Din;          // [4096][2048]
    u16* Kw  = Qw + (size_t)S * Dq;           // [4096][512]
    u16* Vtw = Kw + (size_t)S * Dkv;          // [512][4096]
    u16* Cw   = xb;        // CTX aliases xb (dead after QKV proj)
    u16* Wobt = Qw;        // Wo^T aliases Q (dead after attn)

    // d_out as scratch: fused Wqkv^T bf16 [3072][2048] (12.6 MB <= 33.5 MB)
    u16* Wqkvt = (u16*)d_out;

    dim3 blk(256);
    cast_f2b_kernel<<<dim3((S * Din) / (256 * 8)), blk, 0, stream>>>(x, xb);
    cast_transpose_kernel<<<dim3(Dq  / 64, Din / 64), blk, 0, stream>>>(Wq, Wqkvt, Din, Dq);
    cast_transpose_kernel<<<dim3(Dkv / 64, Din / 64), blk, 0, stream>>>(Wk, Wqkvt + (size_t)2048 * Din, Din, Dkv);
    cast_transpose_kernel<<<dim3(Dkv / 64, Din / 64), blk, 0, stream>>>(Wv, Wqkvt + (size_t)2560 * Din, Din, Dkv);

    gemm_qkv_kernel<<<dim3(3072 / 128, S / 128), blk, 0, stream>>>(
        xb, Wqkvt, Qw, Kw, Vtw, S, Din, QSCALE);

    attn_mfma_kernel<<<dim3(16, 32), blk, 0, stream>>>(Qw, Kw, Vtw, Cw, S);

    cast_transpose_kernel<<<dim3(Dq / 64, Dq / 64), blk, 0, stream>>>(Wo, Wobt, Dq, Dq);
    gemm_out_kernel<<<dim3(Dq / 128, S / 128), blk, 0, stream>>>(Cw, Wobt, bo, out, S, Dq, Dq);
}

// Round 7
// 341.776 us; speedup vs baseline: 1.2274x; 1.0666x over previous
//
#include <hip/hip_runtime.h>
#include <hip/hip_bf16.h>
#include <cstdint>

// ---------------------------------------------------------------------------
// BaseAttention: GQA fwd, b=1 S=4096 d=2048, 32 Q / 8 KV heads, HD=64, causal.
// fp32 in/out; bf16 intermediates.
//
// Round 14 (= Round 13 + double-buffered 2-phase GEMMs):
//  - Both MFMA GEMMs were single-buffered 1-phase: stage -> barrier(vmcnt0)
//    -> compute exposed full DMA latency every 32-K step (~220us combined,
//    ~390 TF). Now: As/Bs[2] double buffer, prologue stage, per K-step ONE
//    barrier then issue next-tile global_load_lds into buf^1 then compute
//    buf (T3 minimum-2-phase; same pattern as the attn k-loop since R7).
//  - Attention unchanged from R13 (123us): double-buffered K/V staging,
//    swapped QK^T, t-outer shared K/V fragment reads, word-granular P
//    repack, q-tile pairing (66 tiles/block uniform).
// ---------------------------------------------------------------------------

typedef unsigned int u32;
typedef unsigned short u16;
typedef __attribute__((ext_vector_type(8))) short bf16x8;
typedef __attribute__((ext_vector_type(4))) float f32x4;
typedef __attribute__((ext_vector_type(2))) u32 u32x2;

typedef __attribute__((address_space(3))) void lds_void_t;
typedef __attribute__((address_space(1))) void gbl_void_t;

__device__ __forceinline__ void gload_lds16(const u16* g, u16* l) {
    __builtin_amdgcn_global_load_lds((const gbl_void_t*)g, (lds_void_t*)l, 16, 0, 0);
}

__device__ __forceinline__ u16 f2bf(float f) {
    union { float f; u32 i; } c; c.f = f;
    return (u16)((c.i + 0x7fffu + ((c.i >> 16) & 1u)) >> 16);
}
__device__ __forceinline__ float bfround(float f) {
    union { float f; u32 i; } c; c.f = f;
    c.i = (c.i + 0x7fffu + ((c.i >> 16) & 1u)) & 0xffff0000u;
    return c.f;
}
__device__ __forceinline__ u32 packbf2(float a, float b) {  // v_cvt_pk_bf16_f32
    union { __hip_bfloat162 h; u32 w; } c;
    c.h = __float22bfloat162_rn(make_float2(a, b));
    return c.w;   // a in low 16, b in high 16
}

// ---------------------------------------------------------------------------
// casts
// ---------------------------------------------------------------------------
__global__ __launch_bounds__(256) void cast_f2b_kernel(
    const float* __restrict__ s, u16* __restrict__ d)
{
    int i = (blockIdx.x * 256 + threadIdx.x) * 8;
    float4 a = *reinterpret_cast<const float4*>(s + i);
    float4 b = *reinterpret_cast<const float4*>(s + i + 4);
    u32 w[4];
    w[0] = packbf2(a.x, a.y); w[1] = packbf2(a.z, a.w);
    w[2] = packbf2(b.x, b.y); w[3] = packbf2(b.z, b.w);
    *reinterpret_cast<uint4*>(d + i) = *reinterpret_cast<const uint4*>(w);
}

__global__ __launch_bounds__(256) void cast_transpose_kernel(
    const float* __restrict__ W, u16* __restrict__ Wt, int K, int N)
{
    __shared__ float tile[64][65];
    const int k0 = blockIdx.y * 64, n0 = blockIdx.x * 64;
    const int t = threadIdx.x;
#pragma unroll
    for (int i = 0; i < 16; ++i) {
        int idx = t + i * 256;
        int r = idx >> 6, c = idx & 63;
        tile[r][c] = W[(size_t)(k0 + r) * N + n0 + c];
    }
    __syncthreads();
#pragma unroll
    for (int i = 0; i < 16; ++i) {
        int idx = t + i * 256;
        int r = idx >> 6, c = idx & 63;
        Wt[(size_t)(n0 + r) * K + k0 + c] = f2bf(tile[c][r]);
    }
}

// ---------------------------------------------------------------------------
// Fused QKV MFMA GEMM, double-buffered 2-phase staging.
// A = xb[4096][2048], Bt = Wqkvt[3072][2048]
// (rows 0..2047 = Wq^T, 2048..2559 = Wk^T, 2560..3071 = Wv^T).
// Column tile routes: Q (bf16, scaled) / K (bf16) / V (bf16 transposed).
// ---------------------------------------------------------------------------
__global__ __launch_bounds__(256) void gemm_qkv_kernel(
    const u16* __restrict__ A, const u16* __restrict__ Bt,
    u16* __restrict__ Qw, u16* __restrict__ Kw, u16* __restrict__ Vtw,
    int M, int K, float qscale)
{
    __shared__ __align__(16) u16 As[2][128][32];
    __shared__ __align__(16) u16 Bs[2][128][32];

    const int tid  = threadIdx.x;
    const int wave = tid >> 6;
    const int lane = tid & 63;
    const int col  = lane & 15;
    const int quad = lane >> 4;
    const int bm = blockIdx.y * 128, bn = blockIdx.x * 128;
    const int mhalf = (wave & 1) * 64, nhalf = (wave >> 1) * 64;

    const int srow = wave * 32 + (lane >> 2);
    const int skch = lane & 3;
    const u16* ga = A  + (size_t)(bm + srow) * K + skch * 8;
    const u16* gb = Bt + (size_t)(bn + srow) * K + skch * 8;
    const int w32 = wave * 32;

    f32x4 acc[4][4];
#pragma unroll
    for (int i = 0; i < 4; ++i)
#pragma unroll
        for (int j = 0; j < 4; ++j) acc[i][j] = (f32x4){0.f, 0.f, 0.f, 0.f};

    // prologue: stage tile 0 into buffer 0
    gload_lds16(ga, &As[0][w32][0]);
    gload_lds16(ga + 16 * K, &As[0][w32 + 16][0]);
    gload_lds16(gb, &Bs[0][w32][0]);
    gload_lds16(gb + 16 * K, &Bs[0][w32 + 16][0]);
    ga += 32; gb += 32;

    for (int k0 = 0; k0 < K; k0 += 32) {
        const int cur = (k0 >> 5) & 1;
        __syncthreads();   // drains DMA into buf[cur]; fences buf[cur^1] reuse

        if (k0 + 32 < K) {  // prefetch next K-tile into the other buffer
            const int nb = cur ^ 1;
            gload_lds16(ga, &As[nb][w32][0]);
            gload_lds16(ga + 16 * K, &As[nb][w32 + 16][0]);
            gload_lds16(gb, &Bs[nb][w32][0]);
            gload_lds16(gb + 16 * K, &Bs[nb][w32 + 16][0]);
            ga += 32; gb += 32;
        }

        bf16x8 af[4], bf[4];
#pragma unroll
        for (int t = 0; t < 4; ++t)
            af[t] = *reinterpret_cast<const bf16x8*>(&As[cur][mhalf + t * 16 + col][quad * 8]);
#pragma unroll
        for (int t = 0; t < 4; ++t)
            bf[t] = *reinterpret_cast<const bf16x8*>(&Bs[cur][nhalf + t * 16 + col][quad * 8]);
#pragma unroll
        for (int tm = 0; tm < 4; ++tm)
#pragma unroll
            for (int tn = 0; tn < 4; ++tn)
                acc[tm][tn] = __builtin_amdgcn_mfma_f32_16x16x32_bf16(
                    af[tm], bf[tn], acc[tm][tn], 0, 0, 0);
    }

    if (bn < 2048) {            // ---- Q route (scaled, row-major [M][2048])
#pragma unroll
        for (int tm = 0; tm < 4; ++tm) {
            int row0 = bm + mhalf + tm * 16 + quad * 4;
#pragma unroll
            for (int r = 0; r < 4; ++r) {
                u16* cp = Qw + (size_t)(row0 + r) * 2048 + bn + nhalf + col;
#pragma unroll
                for (int tn = 0; tn < 4; ++tn)
                    cp[tn * 16] = f2bf(acc[tm][tn][r] * qscale);
            }
        }
    } else if (bn < 2560) {     // ---- K route (row-major [M][512])
        const int cb = bn - 2048;
#pragma unroll
        for (int tm = 0; tm < 4; ++tm) {
            int row0 = bm + mhalf + tm * 16 + quad * 4;
#pragma unroll
            for (int r = 0; r < 4; ++r) {
                u16* cp = Kw + (size_t)(row0 + r) * 512 + cb + nhalf + col;
#pragma unroll
                for (int tn = 0; tn < 4; ++tn)
                    cp[tn * 16] = f2bf(acc[tm][tn][r]);
            }
        }
    } else {                    // ---- V route (transposed [512][M])
        const int cb = bn - 2560;
#pragma unroll
        for (int tn = 0; tn < 4; ++tn) {
            int nrow = cb + nhalf + tn * 16 + col;
#pragma unroll
            for (int tm = 0; tm < 4; ++tm) {
                int m0 = bm + mhalf + tm * 16 + quad * 4;
                ushort4 v;
                v.x = f2bf(acc[tm][tn][0]); v.y = f2bf(acc[tm][tn][1]);
                v.z = f2bf(acc[tm][tn][2]); v.w = f2bf(acc[tm][tn][3]);
                *reinterpret_cast<ushort4*>(&Vtw[(size_t)nrow * M + m0]) = v;
            }
        }
    }
}

// ---------------------------------------------------------------------------
// Out-projection MFMA GEMM, double-buffered 2-phase staging.
// fp32 output + bias (bf16-rounded values).
// ---------------------------------------------------------------------------
__global__ __launch_bounds__(256) void gemm_out_kernel(
    const u16* __restrict__ A, const u16* __restrict__ Bt,
    const float* __restrict__ bias, float* __restrict__ Co,
    int M, int N, int K)
{
    __shared__ __align__(16) u16 As[2][128][32];
    __shared__ __align__(16) u16 Bs[2][128][32];

    const int tid  = threadIdx.x;
    const int wave = tid >> 6;
    const int lane = tid & 63;
    const int col  = lane & 15;
    const int quad = lane >> 4;
    const int bm = blockIdx.y * 128, bn = blockIdx.x * 128;
    const int mhalf = (wave & 1) * 64, nhalf = (wave >> 1) * 64;

    const int srow = wave * 32 + (lane >> 2);
    const int skch = lane & 3;
    const u16* ga = A  + (size_t)(bm + srow) * K + skch * 8;
    const u16* gb = Bt + (size_t)(bn + srow) * K + skch * 8;
    const int w32 = wave * 32;

    f32x4 acc[4][4];
#pragma unroll
    for (int i = 0; i < 4; ++i)
#pragma unroll
        for (int j = 0; j < 4; ++j) acc[i][j] = (f32x4){0.f, 0.f, 0.f, 0.f};

    // prologue: stage tile 0 into buffer 0
    gload_lds16(ga, &As[0][w32][0]);
    gload_lds16(ga + 16 * K, &As[0][w32 + 16][0]);
    gload_lds16(gb, &Bs[0][w32][0]);
    gload_lds16(gb + 16 * K, &Bs[0][w32 + 16][0]);
    ga += 32; gb += 32;

    for (int k0 = 0; k0 < K; k0 += 32) {
        const int cur = (k0 >> 5) & 1;
        __syncthreads();   // drains DMA into buf[cur]; fences buf[cur^1] reuse

        if (k0 + 32 < K) {  // prefetch next K-tile into the other buffer
            const int nb = cur ^ 1;
            gload_lds16(ga, &As[nb][w32][0]);
            gload_lds16(ga + 16 * K, &As[nb][w32 + 16][0]);
            gload_lds16(gb, &Bs[nb][w32][0]);
            gload_lds16(gb + 16 * K, &Bs[nb][w32 + 16][0]);
            ga += 32; gb += 32;
        }

        bf16x8 af[4], bf[4];
#pragma unroll
        for (int t = 0; t < 4; ++t)
            af[t] = *reinterpret_cast<const bf16x8*>(&As[cur][mhalf + t * 16 + col][quad * 8]);
#pragma unroll
        for (int t = 0; t < 4; ++t)
            bf[t] = *reinterpret_cast<const bf16x8*>(&Bs[cur][nhalf + t * 16 + col][quad * 8]);
#pragma unroll
        for (int tm = 0; tm < 4; ++tm)
#pragma unroll
            for (int tn = 0; tn < 4; ++tn)
                acc[tm][tn] = __builtin_amdgcn_mfma_f32_16x16x32_bf16(
                    af[tm], bf[tn], acc[tm][tn], 0, 0, 0);
    }

    float bj[4];
#pragma unroll
    for (int tn = 0; tn < 4; ++tn) bj[tn] = bias[bn + nhalf + tn * 16 + col];
#pragma unroll
    for (int tm = 0; tm < 4; ++tm) {
        int row0 = bm + mhalf + tm * 16 + quad * 4;
#pragma unroll
        for (int r = 0; r < 4; ++r) {
            float* cp = Co + (size_t)(row0 + r) * N + bn + nhalf + col;
#pragma unroll
            for (int tn = 0; tn < 4; ++tn)
                cp[tn * 16] = bfround(acc[tm][tn][r] + bj[tn]);
        }
    }
}

// ---------------------------------------------------------------------------
// Flash attention, fixed-offset softmax, double-buffered K/V staging,
// SWAPPED QK^T (mfma(K,Q)): D[key][qrow]; acc init -16 folds softmax offset.
// t-outer phases: each K/V fragment read once from LDS feeds both mt MFMAs.
// Pu[4][1024]: both mt's packed P live; single lgkm drain per k-tile.
// Causal balance: block = q-tile pair (31-p heavy, then p): 66 tiles/block.
// ---------------------------------------------------------------------------
__global__ __launch_bounds__(256, 2) void attn_mfma_kernel(
    const u16* __restrict__ Q,
    const u16* __restrict__ Kd,
    const u16* __restrict__ Vt,
    u16* __restrict__ CTX,
    int S)
{
    __shared__ __align__(16) u16 Ks[2][64][64];
    __shared__ __align__(16) u16 Vs[2][64][64];
    __shared__ __align__(16) u32 Pu[4][1024];

    const int pairi = blockIdx.x;          // 0..15
    const int h    = blockIdx.y;
    const int g    = h >> 2;
    const int tid  = threadIdx.x;
    const int wave = tid >> 6;
    const int lane = tid & 63;
    const int col  = lane & 15;
    const int quad = lane >> 4;

    const int srow8 = lane >> 3;
    const int schk  = (lane & 7) ^ srow8;
    const u16* gK = Kd + (size_t)(wave * 16 + srow8) * 512 + g * 64 + schk * 8;
    const u16* gV = Vt + (size_t)(g * 64 + wave * 16 + srow8) * 4096 + schk * 8;

    // Pu word index for packed-P writes (per t: +128 words; per mt: +512)
    const int wbase = ((quad >> 1) * 16 + col) * 4 + (quad & 1) * 2;

#pragma unroll 1
    for (int pass = 0; pass < 2; ++pass) {
        const int qt = pass ? pairi : (31 - pairi);   // heavy pass first
        const int qb = qt * 128;

        bf16x8 qf[2][2];
#pragma unroll
        for (int mt = 0; mt < 2; ++mt) {
            const u16* qp = Q + (size_t)(qb + wave * 32 + mt * 16 + col) * 2048
                            + h * 64 + quad * 8;
            qf[mt][0] = *reinterpret_cast<const bf16x8*>(qp);
            qf[mt][1] = *reinterpret_cast<const bf16x8*>(qp + 32);
        }

        f32x4 o_acc[2][4];
        float l_acc[2];
#pragma unroll
        for (int mt = 0; mt < 2; ++mt) {
            l_acc[mt] = 0.f;
#pragma unroll
            for (int t = 0; t < 4; ++t)
                o_acc[mt][t] = (f32x4){0.f, 0.f, 0.f, 0.f};
        }

        const int ktmax = 2 * qt + 1;

        // prefetch tile 0 into buffer 0
        gload_lds16(gK, &Ks[0][wave * 16][0]);
        gload_lds16(gK + (size_t)8 * 512, &Ks[0][wave * 16 + 8][0]);
        gload_lds16(gV, &Vs[0][wave * 16][0]);
        gload_lds16(gV + 8 * 4096, &Vs[0][wave * 16 + 8][0]);

        for (int kt = 0; kt <= ktmax; ++kt) {
            const int kbase = kt * 64;
            const int cur = kt & 1;
            __syncthreads();   // drains DMA into buf[cur]; fences buf[cur^1] reuse

            if (kt < ktmax) {  // prefetch kt+1 into the other buffer
                const int nb = cur ^ 1;
                const size_t ko = (size_t)(kbase + 64);
                gload_lds16(gK + ko * 512, &Ks[nb][wave * 16][0]);
                gload_lds16(gK + (ko + 8) * 512, &Ks[nb][wave * 16 + 8][0]);
                gload_lds16(gV + ko, &Vs[nb][wave * 16][0]);
                gload_lds16(gV + 8 * 4096 + ko, &Vs[nb][wave * 16 + 8][0]);
            }

            const int base0 = qb + wave * 32;       // mt=0 row base
            if (kbase > base0 + 31) continue;       // whole tile masked (wave-uniform)
            const bool act0 = (kbase <= base0 + 15);  // mt=0 active this tile

            // ---- QK phase (t outer; K frags read once, feed both mt) ----
            f32x4 sc0[4], sc1[4];
#pragma unroll
            for (int t = 0; t < 4; ++t) {
                const int krow = t * 16 + col;
                bf16x8 k0 = *reinterpret_cast<const bf16x8*>(
                    &Ks[cur][krow][((quad    ) ^ (krow & 7)) * 8]);
                bf16x8 k1 = *reinterpret_cast<const bf16x8*>(
                    &Ks[cur][krow][((quad + 4) ^ (krow & 7)) * 8]);
                f32x4 c4 = {-16.f, -16.f, -16.f, -16.f};
                c4 = __builtin_amdgcn_mfma_f32_16x16x32_bf16(k0, qf[1][0], c4, 0, 0, 0);
                c4 = __builtin_amdgcn_mfma_f32_16x16x32_bf16(k1, qf[1][1], c4, 0, 0, 0);
                sc1[t] = c4;
                if (act0) {
                    f32x4 d4 = {-16.f, -16.f, -16.f, -16.f};
                    d4 = __builtin_amdgcn_mfma_f32_16x16x32_bf16(k0, qf[0][0], d4, 0, 0, 0);
                    d4 = __builtin_amdgcn_mfma_f32_16x16x32_bf16(k1, qf[0][1], d4, 0, 0, 0);
                    sc0[t] = d4;
                }
            }

            // ---- causal mask (qrow(mt) = base0 + mt*16 + col) ----
            if (kbase + 63 > base0) {
#pragma unroll
                for (int t = 0; t < 4; ++t) {
                    const int keyq = kbase + t * 16 + quad * 4;
#pragma unroll
                    for (int r = 0; r < 4; ++r) {
                        if (keyq + r > base0 + 16 + col) sc1[t][r] = -1e30f;
                        if (act0 && (keyq + r > base0 + col)) sc0[t][r] = -1e30f;
                    }
                }
            }

            // ---- p = exp2(sc); pack both mt into PV A-fragment words ----
            {
                float ls0 = 0.f, ls1 = 0.f;
#pragma unroll
                for (int t = 0; t < 4; ++t) {
                    float p0 = __builtin_amdgcn_exp2f(sc1[t][0]);
                    float p1 = __builtin_amdgcn_exp2f(sc1[t][1]);
                    float p2 = __builtin_amdgcn_exp2f(sc1[t][2]);
                    float p3 = __builtin_amdgcn_exp2f(sc1[t][3]);
                    ls1 += (p0 + p1) + (p2 + p3);
                    u32x2 w;
                    w.x = packbf2(p0, p1);
                    w.y = packbf2(p2, p3);
                    *reinterpret_cast<u32x2*>(&Pu[wave][512 + wbase + t * 128]) = w;
                    if (act0) {
                        float q0 = __builtin_amdgcn_exp2f(sc0[t][0]);
                        float q1 = __builtin_amdgcn_exp2f(sc0[t][1]);
                        float q2 = __builtin_amdgcn_exp2f(sc0[t][2]);
                        float q3 = __builtin_amdgcn_exp2f(sc0[t][3]);
                        ls0 += (q0 + q1) + (q2 + q3);
                        u32x2 v;
                        v.x = packbf2(q0, q1);
                        v.y = packbf2(q2, q3);
                        *reinterpret_cast<u32x2*>(&Pu[wave][wbase + t * 128]) = v;
                    }
                }
                l_acc[1] += ls1;
                if (act0) l_acc[0] += ls0;
            }

            // single drain of LDS writes (lgkmcnt(0); vmcnt=63 keeps DMA going)
            __builtin_amdgcn_s_waitcnt(0xC07F);
            __builtin_amdgcn_wave_barrier();

            bf16x8 pa1_0 = *reinterpret_cast<const bf16x8*>(&Pu[wave][512 + lane * 4]);
            bf16x8 pa1_1 = *reinterpret_cast<const bf16x8*>(&Pu[wave][768 + lane * 4]);
            bf16x8 pa0_0, pa0_1;
            if (act0) {
                pa0_0 = *reinterpret_cast<const bf16x8*>(&Pu[wave][lane * 4]);
                pa0_1 = *reinterpret_cast<const bf16x8*>(&Pu[wave][256 + lane * 4]);
            }

            // ---- PV phase (t outer; V frags read once, feed both mt) ----
#pragma unroll
            for (int t = 0; t < 4; ++t) {
                const int d = t * 16 + col;
                bf16x8 vb0 = *reinterpret_cast<const bf16x8*>(
                    &Vs[cur][d][((quad    ) ^ (d & 7)) * 8]);
                bf16x8 vb1 = *reinterpret_cast<const bf16x8*>(
                    &Vs[cur][d][((quad + 4) ^ (d & 7)) * 8]);
                o_acc[1][t] = __builtin_amdgcn_mfma_f32_16x16x32_bf16(pa1_0, vb0, o_acc[1][t], 0, 0, 0);
                o_acc[1][t] = __builtin_amdgcn_mfma_f32_16x16x32_bf16(pa1_1, vb1, o_acc[1][t], 0, 0, 0);
                if (act0) {
                    o_acc[0][t] = __builtin_amdgcn_mfma_f32_16x16x32_bf16(pa0_0, vb0, o_acc[0][t], 0, 0, 0);
                    o_acc[0][t] = __builtin_amdgcn_mfma_f32_16x16x32_bf16(pa0_1, vb1, o_acc[0][t], 0, 0, 0);
                }
            }
        }

        // ---- epilogue (per pass) ----
#pragma unroll
        for (int mt = 0; mt < 2; ++mt) {
            // full row-sum for qrow=col lives split across quads: reduce
            float v = l_acc[mt];
            v += __shfl_xor(v, 16, 64);
            v += __shfl_xor(v, 32, 64);
            // redistribute: lane needs l for qrow = quad*4 + r (o_acc row layout)
            const int src0 = (lane & 48) + ((lane >> 4) & 3) * 4;
#pragma unroll
            for (int r = 0; r < 4; ++r) {
                const float lv = __shfl(v, src0 + r, 64);
                const float inv = 1.f / lv;
                const int row = qb + wave * 32 + mt * 16 + quad * 4 + r;
                u16* cp = CTX + (size_t)row * 2048 + h * 64;
#pragma unroll
                for (int t = 0; t < 4; ++t)
                    cp[t * 16 + col] = f2bf(o_acc[mt][t][r] * inv);
            }
        }
    }
}

// ---------------------------------------------------------------------------
extern "C" void kernel_launch(void* const* d_in, const int* in_sizes, int n_in,
                              void* d_out, int out_size, void* d_ws, size_t ws_size,
                              hipStream_t stream)
{
    const float* x  = (const float*)d_in[0];   // [4096, 2048]
    const float* Wq = (const float*)d_in[1];   // [2048, 2048]
    const float* Wk = (const float*)d_in[2];   // [2048, 512]
    const float* Wv = (const float*)d_in[3];   // [2048, 512]
    const float* Wo = (const float*)d_in[4];   // [2048, 2048]
    const float* bo = (const float*)d_in[5];   // [2048]
    float* out = (float*)d_out;                // [4096, 2048]

    const int S = 4096, Din = 2048, Dq = 2048, Dkv = 512;
    const float QSCALE = 0.125f * 1.44269504f; // 1/sqrt(64) * log2(e)

    u16* xb  = (u16*)d_ws;                    // [4096][2048]
    u16* Qw  = xb + (size_t)S * Din;          // [4096][2048]
    u16* Kw  = Qw + (size_t)S * Dq;           // [4096][512]
    u16* Vtw = Kw + (size_t)S * Dkv;          // [512][4096]
    u16* Cw   = xb;        // CTX aliases xb (dead after QKV proj)
    u16* Wobt = Qw;        // Wo^T aliases Q (dead after attn)

    // d_out as scratch: fused Wqkv^T bf16 [3072][2048] (12.6 MB <= 33.5 MB)
    u16* Wqkvt = (u16*)d_out;

    dim3 blk(256);
    cast_f2b_kernel<<<dim3((S * Din) / (256 * 8)), blk, 0, stream>>>(x, xb);
    cast_transpose_kernel<<<dim3(Dq  / 64, Din / 64), blk, 0, stream>>>(Wq, Wqkvt, Din, Dq);
    cast_transpose_kernel<<<dim3(Dkv / 64, Din / 64), blk, 0, stream>>>(Wk, Wqkvt + (size_t)2048 * Din, Din, Dkv);
    cast_transpose_kernel<<<dim3(Dkv / 64, Din / 64), blk, 0, stream>>>(Wv, Wqkvt + (size_t)2560 * Din, Din, Dkv);

    gemm_qkv_kernel<<<dim3(3072 / 128, S / 128), blk, 0, stream>>>(
        xb, Wqkvt, Qw, Kw, Vtw, S, Din, QSCALE);

    attn_mfma_kernel<<<dim3(16, 32), blk, 0, stream>>>(Qw, Kw, Vtw, Cw, S);

    cast_transpose_kernel<<<dim3(Dq / 64, Dq / 64), blk, 0, stream>>>(Wo, Wobt, Dq, Dq);
    gemm_out_kernel<<<dim3(Dq / 128, S / 128), blk, 0, stream>>>(Cw, Wobt, bo, out, S, Dq, Dq);
}

// Round 8
// 336.500 us; speedup vs baseline: 1.2467x; 1.0157x over previous
//
#include <hip/hip_runtime.h>
#include <hip/hip_bf16.h>
#include <cstdint>

// ---------------------------------------------------------------------------
// BaseAttention: GQA fwd, b=1 S=4096 d=2048, 32 Q / 8 KV heads, HD=64, causal.
// fp32 in/out; bf16 intermediates.
//
// Round 15 (= Round 14 + attn KVBLK 64->128: one barrier per 128 keys):
//  - R14 attn counters: MfmaUtil 23.6 + VALUBusy 43.9 = ~67% busy; ~33%
//    is the per-64-key __syncthreads() vmcnt(0) drain. Now K/V tiles are
//    128 keys (Ks[2][128][64], Vs[2][64][128], 80 KiB total with Pu ->
//    still exactly 2 blocks/CU); per tile: 1 barrier + prefetch, then the
//    64-key body runs twice (h64 halves; softmax/Pu per-wave, unchanged).
//  - V staging swizzle tracks true row parity for j-odd sub-loads
//    ((j*4+vrow)&7 = vrow^4 -> dual gV0/gV1 base pointers). Each pass
//    opens with __syncthreads() (ktmax parity no longer guarantees the
//    prior pass's buf-0 readers are fenced before prologue DMA).
//  - GEMMs (2-phase double-buffered) + casts unchanged from R14.
// ---------------------------------------------------------------------------

typedef unsigned int u32;
typedef unsigned short u16;
typedef __attribute__((ext_vector_type(8))) short bf16x8;
typedef __attribute__((ext_vector_type(4))) float f32x4;
typedef __attribute__((ext_vector_type(2))) u32 u32x2;

typedef __attribute__((address_space(3))) void lds_void_t;
typedef __attribute__((address_space(1))) void gbl_void_t;

__device__ __forceinline__ void gload_lds16(const u16* g, u16* l) {
    __builtin_amdgcn_global_load_lds((const gbl_void_t*)g, (lds_void_t*)l, 16, 0, 0);
}

__device__ __forceinline__ u16 f2bf(float f) {
    union { float f; u32 i; } c; c.f = f;
    return (u16)((c.i + 0x7fffu + ((c.i >> 16) & 1u)) >> 16);
}
__device__ __forceinline__ float bfround(float f) {
    union { float f; u32 i; } c; c.f = f;
    c.i = (c.i + 0x7fffu + ((c.i >> 16) & 1u)) & 0xffff0000u;
    return c.f;
}
__device__ __forceinline__ u32 packbf2(float a, float b) {  // v_cvt_pk_bf16_f32
    union { __hip_bfloat162 h; u32 w; } c;
    c.h = __float22bfloat162_rn(make_float2(a, b));
    return c.w;   // a in low 16, b in high 16
}

// ---------------------------------------------------------------------------
// casts
// ---------------------------------------------------------------------------
__global__ __launch_bounds__(256) void cast_f2b_kernel(
    const float* __restrict__ s, u16* __restrict__ d)
{
    int i = (blockIdx.x * 256 + threadIdx.x) * 8;
    float4 a = *reinterpret_cast<const float4*>(s + i);
    float4 b = *reinterpret_cast<const float4*>(s + i + 4);
    u32 w[4];
    w[0] = packbf2(a.x, a.y); w[1] = packbf2(a.z, a.w);
    w[2] = packbf2(b.x, b.y); w[3] = packbf2(b.z, b.w);
    *reinterpret_cast<uint4*>(d + i) = *reinterpret_cast<const uint4*>(w);
}

__global__ __launch_bounds__(256) void cast_transpose_kernel(
    const float* __restrict__ W, u16* __restrict__ Wt, int K, int N)
{
    __shared__ float tile[64][65];
    const int k0 = blockIdx.y * 64, n0 = blockIdx.x * 64;
    const int t = threadIdx.x;
#pragma unroll
    for (int i = 0; i < 16; ++i) {
        int idx = t + i * 256;
        int r = idx >> 6, c = idx & 63;
        tile[r][c] = W[(size_t)(k0 + r) * N + n0 + c];
    }
    __syncthreads();
#pragma unroll
    for (int i = 0; i < 16; ++i) {
        int idx = t + i * 256;
        int r = idx >> 6, c = idx & 63;
        Wt[(size_t)(n0 + r) * K + k0 + c] = f2bf(tile[c][r]);
    }
}

// ---------------------------------------------------------------------------
// Fused QKV MFMA GEMM, double-buffered 2-phase staging.
// A = xb[4096][2048], Bt = Wqkvt[3072][2048]
// (rows 0..2047 = Wq^T, 2048..2559 = Wk^T, 2560..3071 = Wv^T).
// Column tile routes: Q (bf16, scaled) / K (bf16) / V (bf16 transposed).
// ---------------------------------------------------------------------------
__global__ __launch_bounds__(256) void gemm_qkv_kernel(
    const u16* __restrict__ A, const u16* __restrict__ Bt,
    u16* __restrict__ Qw, u16* __restrict__ Kw, u16* __restrict__ Vtw,
    int M, int K, float qscale)
{
    __shared__ __align__(16) u16 As[2][128][32];
    __shared__ __align__(16) u16 Bs[2][128][32];

    const int tid  = threadIdx.x;
    const int wave = tid >> 6;
    const int lane = tid & 63;
    const int col  = lane & 15;
    const int quad = lane >> 4;
    const int bm = blockIdx.y * 128, bn = blockIdx.x * 128;
    const int mhalf = (wave & 1) * 64, nhalf = (wave >> 1) * 64;

    const int srow = wave * 32 + (lane >> 2);
    const int skch = lane & 3;
    const u16* ga = A  + (size_t)(bm + srow) * K + skch * 8;
    const u16* gb = Bt + (size_t)(bn + srow) * K + skch * 8;
    const int w32 = wave * 32;

    f32x4 acc[4][4];
#pragma unroll
    for (int i = 0; i < 4; ++i)
#pragma unroll
        for (int j = 0; j < 4; ++j) acc[i][j] = (f32x4){0.f, 0.f, 0.f, 0.f};

    // prologue: stage tile 0 into buffer 0
    gload_lds16(ga, &As[0][w32][0]);
    gload_lds16(ga + 16 * K, &As[0][w32 + 16][0]);
    gload_lds16(gb, &Bs[0][w32][0]);
    gload_lds16(gb + 16 * K, &Bs[0][w32 + 16][0]);
    ga += 32; gb += 32;

    for (int k0 = 0; k0 < K; k0 += 32) {
        const int cur = (k0 >> 5) & 1;
        __syncthreads();   // drains DMA into buf[cur]; fences buf[cur^1] reuse

        if (k0 + 32 < K) {  // prefetch next K-tile into the other buffer
            const int nb = cur ^ 1;
            gload_lds16(ga, &As[nb][w32][0]);
            gload_lds16(ga + 16 * K, &As[nb][w32 + 16][0]);
            gload_lds16(gb, &Bs[nb][w32][0]);
            gload_lds16(gb + 16 * K, &Bs[nb][w32 + 16][0]);
            ga += 32; gb += 32;
        }

        bf16x8 af[4], bf[4];
#pragma unroll
        for (int t = 0; t < 4; ++t)
            af[t] = *reinterpret_cast<const bf16x8*>(&As[cur][mhalf + t * 16 + col][quad * 8]);
#pragma unroll
        for (int t = 0; t < 4; ++t)
            bf[t] = *reinterpret_cast<const bf16x8*>(&Bs[cur][nhalf + t * 16 + col][quad * 8]);
#pragma unroll
        for (int tm = 0; tm < 4; ++tm)
#pragma unroll
            for (int tn = 0; tn < 4; ++tn)
                acc[tm][tn] = __builtin_amdgcn_mfma_f32_16x16x32_bf16(
                    af[tm], bf[tn], acc[tm][tn], 0, 0, 0);
    }

    if (bn < 2048) {            // ---- Q route (scaled, row-major [M][2048])
#pragma unroll
        for (int tm = 0; tm < 4; ++tm) {
            int row0 = bm + mhalf + tm * 16 + quad * 4;
#pragma unroll
            for (int r = 0; r < 4; ++r) {
                u16* cp = Qw + (size_t)(row0 + r) * 2048 + bn + nhalf + col;
#pragma unroll
                for (int tn = 0; tn < 4; ++tn)
                    cp[tn * 16] = f2bf(acc[tm][tn][r] * qscale);
            }
        }
    } else if (bn < 2560) {     // ---- K route (row-major [M][512])
        const int cb = bn - 2048;
#pragma unroll
        for (int tm = 0; tm < 4; ++tm) {
            int row0 = bm + mhalf + tm * 16 + quad * 4;
#pragma unroll
            for (int r = 0; r < 4; ++r) {
                u16* cp = Kw + (size_t)(row0 + r) * 512 + cb + nhalf + col;
#pragma unroll
                for (int tn = 0; tn < 4; ++tn)
                    cp[tn * 16] = f2bf(acc[tm][tn][r]);
            }
        }
    } else {                    // ---- V route (transposed [512][M])
        const int cb = bn - 2560;
#pragma unroll
        for (int tn = 0; tn < 4; ++tn) {
            int nrow = cb + nhalf + tn * 16 + col;
#pragma unroll
            for (int tm = 0; tm < 4; ++tm) {
                int m0 = bm + mhalf + tm * 16 + quad * 4;
                ushort4 v;
                v.x = f2bf(acc[tm][tn][0]); v.y = f2bf(acc[tm][tn][1]);
                v.z = f2bf(acc[tm][tn][2]); v.w = f2bf(acc[tm][tn][3]);
                *reinterpret_cast<ushort4*>(&Vtw[(size_t)nrow * M + m0]) = v;
            }
        }
    }
}

// ---------------------------------------------------------------------------
// Out-projection MFMA GEMM, double-buffered 2-phase staging.
// fp32 output + bias (bf16-rounded values).
// ---------------------------------------------------------------------------
__global__ __launch_bounds__(256) void gemm_out_kernel(
    const u16* __restrict__ A, const u16* __restrict__ Bt,
    const float* __restrict__ bias, float* __restrict__ Co,
    int M, int N, int K)
{
    __shared__ __align__(16) u16 As[2][128][32];
    __shared__ __align__(16) u16 Bs[2][128][32];

    const int tid  = threadIdx.x;
    const int wave = tid >> 6;
    const int lane = tid & 63;
    const int col  = lane & 15;
    const int quad = lane >> 4;
    const int bm = blockIdx.y * 128, bn = blockIdx.x * 128;
    const int mhalf = (wave & 1) * 64, nhalf = (wave >> 1) * 64;

    const int srow = wave * 32 + (lane >> 2);
    const int skch = lane & 3;
    const u16* ga = A  + (size_t)(bm + srow) * K + skch * 8;
    const u16* gb = Bt + (size_t)(bn + srow) * K + skch * 8;
    const int w32 = wave * 32;

    f32x4 acc[4][4];
#pragma unroll
    for (int i = 0; i < 4; ++i)
#pragma unroll
        for (int j = 0; j < 4; ++j) acc[i][j] = (f32x4){0.f, 0.f, 0.f, 0.f};

    // prologue: stage tile 0 into buffer 0
    gload_lds16(ga, &As[0][w32][0]);
    gload_lds16(ga + 16 * K, &As[0][w32 + 16][0]);
    gload_lds16(gb, &Bs[0][w32][0]);
    gload_lds16(gb + 16 * K, &Bs[0][w32 + 16][0]);
    ga += 32; gb += 32;

    for (int k0 = 0; k0 < K; k0 += 32) {
        const int cur = (k0 >> 5) & 1;
        __syncthreads();   // drains DMA into buf[cur]; fences buf[cur^1] reuse

        if (k0 + 32 < K) {  // prefetch next K-tile into the other buffer
            const int nb = cur ^ 1;
            gload_lds16(ga, &As[nb][w32][0]);
            gload_lds16(ga + 16 * K, &As[nb][w32 + 16][0]);
            gload_lds16(gb, &Bs[nb][w32][0]);
            gload_lds16(gb + 16 * K, &Bs[nb][w32 + 16][0]);
            ga += 32; gb += 32;
        }

        bf16x8 af[4], bf[4];
#pragma unroll
        for (int t = 0; t < 4; ++t)
            af[t] = *reinterpret_cast<const bf16x8*>(&As[cur][mhalf + t * 16 + col][quad * 8]);
#pragma unroll
        for (int t = 0; t < 4; ++t)
            bf[t] = *reinterpret_cast<const bf16x8*>(&Bs[cur][nhalf + t * 16 + col][quad * 8]);
#pragma unroll
        for (int tm = 0; tm < 4; ++tm)
#pragma unroll
            for (int tn = 0; tn < 4; ++tn)
                acc[tm][tn] = __builtin_amdgcn_mfma_f32_16x16x32_bf16(
                    af[tm], bf[tn], acc[tm][tn], 0, 0, 0);
    }

    float bj[4];
#pragma unroll
    for (int tn = 0; tn < 4; ++tn) bj[tn] = bias[bn + nhalf + tn * 16 + col];
#pragma unroll
    for (int tm = 0; tm < 4; ++tm) {
        int row0 = bm + mhalf + tm * 16 + quad * 4;
#pragma unroll
        for (int r = 0; r < 4; ++r) {
            float* cp = Co + (size_t)(row0 + r) * N + bn + nhalf + col;
#pragma unroll
            for (int tn = 0; tn < 4; ++tn)
                cp[tn * 16] = bfround(acc[tm][tn][r] + bj[tn]);
        }
    }
}

// ---------------------------------------------------------------------------
// Flash attention, fixed-offset softmax, double-buffered K/V staging with
// KVBLK=128 (1 barrier per 128 keys), SWAPPED QK^T (mfma(K,Q)), word-granular
// P repack via Pu, acc init -16 folds softmax offset. Per 128-key tile the
// 64-key body runs twice (h64 halves). t-outer shared K/V fragment reads.
// Causal balance: block = q-tile pair (31-p heavy, then p): 34 tiles/block.
// Ks[2][128][64] (key-major), Vs[2][64][128] (d-major), Pu[4][1024]: 80 KiB.
// ---------------------------------------------------------------------------
__global__ __launch_bounds__(256, 2) void attn_mfma_kernel(
    const u16* __restrict__ Q,
    const u16* __restrict__ Kd,
    const u16* __restrict__ Vt,
    u16* __restrict__ CTX,
    int S)
{
    __shared__ __align__(16) u16 Ks[2][128][64];
    __shared__ __align__(16) u16 Vs[2][64][128];
    __shared__ __align__(16) u32 Pu[4][1024];

    const int pairi = blockIdx.x;          // 0..15
    const int h    = blockIdx.y;
    const int g    = h >> 2;
    const int tid  = threadIdx.x;
    const int wave = tid >> 6;
    const int lane = tid & 63;
    const int col  = lane & 15;
    const int quad = lane >> 4;

    // K staging: lane covers key-row (wave*32 + j*8 + srow8), dim-chunk
    // schk (XOR by row&7 == srow8). 4 gloads/wave per 128-key tile.
    const int srow8 = lane >> 3;
    const int schk  = (lane & 7) ^ srow8;
    const u16* gK = Kd + (size_t)(wave * 32 + srow8) * 512 + g * 64 + schk * 8;

    // V staging: Vs[d][128 keys]; lane covers d-row (wave*16 + j*4 + vrow),
    // key-half vhalf, key-chunk XOR by true row&7: (j*4+vrow)&7 = vrow^(4*(j&1))
    // -> two base pointers (gV0 even j, gV1 odd j).
    const int vrow  = lane >> 4;          // 0..3
    const int vhalf = (lane >> 3) & 1;
    const int vchk0 = (lane & 7) ^ vrow;
    const u16* gVbase = Vt + (size_t)(g * 64 + wave * 16 + vrow) * 4096 + vhalf * 64;
    const u16* gV0 = gVbase + vchk0 * 8;
    const u16* gV1 = gVbase + (vchk0 ^ 4) * 8;

    // Pu word index for packed-P writes (per t: +128 words; per mt: +512)
    const int wbase = ((quad >> 1) * 16 + col) * 4 + (quad & 1) * 2;

#pragma unroll 1
    for (int pass = 0; pass < 2; ++pass) {
        const int qt = pass ? pairi : (31 - pairi);   // heavy pass first
        const int qb = qt * 128;

        bf16x8 qf[2][2];
#pragma unroll
        for (int mt = 0; mt < 2; ++mt) {
            const u16* qp = Q + (size_t)(qb + wave * 32 + mt * 16 + col) * 2048
                            + h * 64 + quad * 8;
            qf[mt][0] = *reinterpret_cast<const bf16x8*>(qp);
            qf[mt][1] = *reinterpret_cast<const bf16x8*>(qp + 32);
        }

        f32x4 o_acc[2][4];
        float l_acc[2];
#pragma unroll
        for (int mt = 0; mt < 2; ++mt) {
            l_acc[mt] = 0.f;
#pragma unroll
            for (int t = 0; t < 4; ++t)
                o_acc[mt][t] = (f32x4){0.f, 0.f, 0.f, 0.f};
        }

        const int ktmax = qt;   // tiles of 128 keys: 0..qt

        // fence prior-pass buf readers, then stage tile 0 into buffer 0
        __syncthreads();
#pragma unroll
        for (int j = 0; j < 4; ++j) {
            gload_lds16(gK + (size_t)(j * 8) * 512, &Ks[0][wave * 32 + j * 8][0]);
            const u16* gv = (j & 1) ? gV1 : gV0;
            gload_lds16(gv + (size_t)(j * 4) * 4096, &Vs[0][wave * 16 + j * 4][0]);
        }

        for (int kt = 0; kt <= ktmax; ++kt) {
            const int cur = kt & 1;
            __syncthreads();   // drains DMA into buf[cur]; fences buf[cur^1] reuse

            if (kt < ktmax) {  // prefetch kt+1 into the other buffer
                const int nb = cur ^ 1;
                const size_t ko = (size_t)(kt + 1) * 128;
#pragma unroll
                for (int j = 0; j < 4; ++j) {
                    gload_lds16(gK + (ko + j * 8) * 512, &Ks[nb][wave * 32 + j * 8][0]);
                    const u16* gv = (j & 1) ? gV1 : gV0;
                    gload_lds16(gv + ko + (size_t)(j * 4) * 4096, &Vs[nb][wave * 16 + j * 4][0]);
                }
            }

            const int base0 = qb + wave * 32;       // mt=0 row base

#pragma unroll
            for (int h64 = 0; h64 < 2; ++h64) {
                const int kbase = kt * 128 + h64 * 64;
                if (kbase > base0 + 31) continue;       // both mt masked
                const bool act0 = (kbase <= base0 + 15);
                const int rbase = h64 * 64;

                // ---- QK phase (t outer; K frags read once, feed both mt) ----
                f32x4 sc0[4], sc1[4];
#pragma unroll
                for (int t = 0; t < 4; ++t) {
                    const int krow = t * 16 + col;
                    bf16x8 k0 = *reinterpret_cast<const bf16x8*>(
                        &Ks[cur][rbase + krow][((quad    ) ^ (krow & 7)) * 8]);
                    bf16x8 k1 = *reinterpret_cast<const bf16x8*>(
                        &Ks[cur][rbase + krow][((quad + 4) ^ (krow & 7)) * 8]);
                    f32x4 c4 = {-16.f, -16.f, -16.f, -16.f};
                    c4 = __builtin_amdgcn_mfma_f32_16x16x32_bf16(k0, qf[1][0], c4, 0, 0, 0);
                    c4 = __builtin_amdgcn_mfma_f32_16x16x32_bf16(k1, qf[1][1], c4, 0, 0, 0);
                    sc1[t] = c4;
                    if (act0) {
                        f32x4 d4 = {-16.f, -16.f, -16.f, -16.f};
                        d4 = __builtin_amdgcn_mfma_f32_16x16x32_bf16(k0, qf[0][0], d4, 0, 0, 0);
                        d4 = __builtin_amdgcn_mfma_f32_16x16x32_bf16(k1, qf[0][1], d4, 0, 0, 0);
                        sc0[t] = d4;
                    }
                }

                // ---- causal mask (qrow(mt) = base0 + mt*16 + col) ----
                if (kbase + 63 > base0) {
#pragma unroll
                    for (int t = 0; t < 4; ++t) {
                        const int keyq = kbase + t * 16 + quad * 4;
#pragma unroll
                        for (int r = 0; r < 4; ++r) {
                            if (keyq + r > base0 + 16 + col) sc1[t][r] = -1e30f;
                            if (act0 && (keyq + r > base0 + col)) sc0[t][r] = -1e30f;
                        }
                    }
                }

                // ---- p = exp2(sc); pack both mt into PV A-fragment words ----
                {
                    float ls0 = 0.f, ls1 = 0.f;
#pragma unroll
                    for (int t = 0; t < 4; ++t) {
                        float p0 = __builtin_amdgcn_exp2f(sc1[t][0]);
                        float p1 = __builtin_amdgcn_exp2f(sc1[t][1]);
                        float p2 = __builtin_amdgcn_exp2f(sc1[t][2]);
                        float p3 = __builtin_amdgcn_exp2f(sc1[t][3]);
                        ls1 += (p0 + p1) + (p2 + p3);
                        u32x2 w;
                        w.x = packbf2(p0, p1);
                        w.y = packbf2(p2, p3);
                        *reinterpret_cast<u32x2*>(&Pu[wave][512 + wbase + t * 128]) = w;
                        if (act0) {
                            float q0 = __builtin_amdgcn_exp2f(sc0[t][0]);
                            float q1 = __builtin_amdgcn_exp2f(sc0[t][1]);
                            float q2 = __builtin_amdgcn_exp2f(sc0[t][2]);
                            float q3 = __builtin_amdgcn_exp2f(sc0[t][3]);
                            ls0 += (q0 + q1) + (q2 + q3);
                            u32x2 v;
                            v.x = packbf2(q0, q1);
                            v.y = packbf2(q2, q3);
                            *reinterpret_cast<u32x2*>(&Pu[wave][wbase + t * 128]) = v;
                        }
                    }
                    l_acc[1] += ls1;
                    if (act0) l_acc[0] += ls0;
                }

                // drain LDS writes only (lgkmcnt(0); vmcnt=63 keeps DMA going)
                __builtin_amdgcn_s_waitcnt(0xC07F);
                __builtin_amdgcn_wave_barrier();

                bf16x8 pa1_0 = *reinterpret_cast<const bf16x8*>(&Pu[wave][512 + lane * 4]);
                bf16x8 pa1_1 = *reinterpret_cast<const bf16x8*>(&Pu[wave][768 + lane * 4]);
                bf16x8 pa0_0, pa0_1;
                if (act0) {
                    pa0_0 = *reinterpret_cast<const bf16x8*>(&Pu[wave][lane * 4]);
                    pa0_1 = *reinterpret_cast<const bf16x8*>(&Pu[wave][256 + lane * 4]);
                }

                // ---- PV phase (t outer; V frags read once, feed both mt) ----
#pragma unroll
                for (int t = 0; t < 4; ++t) {
                    const int d = t * 16 + col;
                    bf16x8 vb0 = *reinterpret_cast<const bf16x8*>(
                        &Vs[cur][d][rbase + ((quad    ) ^ (d & 7)) * 8]);
                    bf16x8 vb1 = *reinterpret_cast<const bf16x8*>(
                        &Vs[cur][d][rbase + ((quad + 4) ^ (d & 7)) * 8]);
                    o_acc[1][t] = __builtin_amdgcn_mfma_f32_16x16x32_bf16(pa1_0, vb0, o_acc[1][t], 0, 0, 0);
                    o_acc[1][t] = __builtin_amdgcn_mfma_f32_16x16x32_bf16(pa1_1, vb1, o_acc[1][t], 0, 0, 0);
                    if (act0) {
                        o_acc[0][t] = __builtin_amdgcn_mfma_f32_16x16x32_bf16(pa0_0, vb0, o_acc[0][t], 0, 0, 0);
                        o_acc[0][t] = __builtin_amdgcn_mfma_f32_16x16x32_bf16(pa0_1, vb1, o_acc[0][t], 0, 0, 0);
                    }
                }
            }
        }

        // ---- epilogue (per pass) ----
#pragma unroll
        for (int mt = 0; mt < 2; ++mt) {
            // full row-sum for qrow=col lives split across quads: reduce
            float v = l_acc[mt];
            v += __shfl_xor(v, 16, 64);
            v += __shfl_xor(v, 32, 64);
            // redistribute: lane needs l for qrow = quad*4 + r (o_acc row layout)
            const int src0 = (lane & 48) + ((lane >> 4) & 3) * 4;
#pragma unroll
            for (int r = 0; r < 4; ++r) {
                const float lv = __shfl(v, src0 + r, 64);
                const float inv = 1.f / lv;
                const int row = qb + wave * 32 + mt * 16 + quad * 4 + r;
                u16* cp = CTX + (size_t)row * 2048 + h * 64;
#pragma unroll
                for (int t = 0; t < 4; ++t)
                    cp[t * 16 + col] = f2bf(o_acc[mt][t][r] * inv);
            }
        }
    }
}

// ---------------------------------------------------------------------------
extern "C" void kernel_launch(void* const* d_in, const int* in_sizes, int n_in,
                              void* d_out, int out_size, void* d_ws, size_t ws_size,
                              hipStream_t stream)
{
    const float* x  = (const float*)d_in[0];   // [4096, 2048]
    const float* Wq = (const float*)d_in[1];   // [2048, 2048]
    const float* Wk = (const float*)d_in[2];   // [2048, 512]
    const float* Wv = (const float*)d_in[3];   // [2048, 512]
    const float* Wo = (const float*)d_in[4];   // [2048, 2048]
    const float* bo = (const float*)d_in[5];   // [2048]
    float* out = (float*)d_out;                // [4096, 2048]

    const int S = 4096, Din = 2048, Dq = 2048, Dkv = 512;
    const float QSCALE = 0.125f * 1.44269504f; // 1/sqrt(64) * log2(e)

    u16* xb  = (u16*)d_ws;                    // [4096][2048]
    u16* Qw  = xb + (size_t)S * Din;          // [4096][2048]
    u16* Kw  = Qw + (size_t)S * Dq;           // [4096][512]
    u16* Vtw = Kw + (size_t)S * Dkv;          // [512][4096]
    u16* Cw   = xb;        // CTX aliases xb (dead after QKV proj)
    u16* Wobt = Qw;        // Wo^T aliases Q (dead after attn)

    // d_out as scratch: fused Wqkv^T bf16 [3072][2048] (12.6 MB <= 33.5 MB)
    u16* Wqkvt = (u16*)d_out;

    dim3 blk(256);
    cast_f2b_kernel<<<dim3((S * Din) / (256 * 8)), blk, 0, stream>>>(x, xb);
    cast_transpose_kernel<<<dim3(Dq  / 64, Din / 64), blk, 0, stream>>>(Wq, Wqkvt, Din, Dq);
    cast_transpose_kernel<<<dim3(Dkv / 64, Din / 64), blk, 0, stream>>>(Wk, Wqkvt + (size_t)2048 * Din, Din, Dkv);
    cast_transpose_kernel<<<dim3(Dkv / 64, Din / 64), blk, 0, stream>>>(Wv, Wqkvt + (size_t)2560 * Din, Din, Dkv);

    gemm_qkv_kernel<<<dim3(3072 / 128, S / 128), blk, 0, stream>>>(
        xb, Wqkvt, Qw, Kw, Vtw, S, Din, QSCALE);

    attn_mfma_kernel<<<dim3(16, 32), blk, 0, stream>>>(Qw, Kw, Vtw, Cw, S);

    cast_transpose_kernel<<<dim3(Dq / 64, Dq / 64), blk, 0, stream>>>(Wo, Wobt, Dq, Dq);
    gemm_out_kernel<<<dim3(Dq / 128, S / 128), blk, 0, stream>>>(Cw, Wobt, bo, out, S, Dq, Dq);
}

// Round 9
// 331.503 us; speedup vs baseline: 1.2655x; 1.0151x over previous
//
#include <hip/hip_runtime.h>
#include <hip/hip_bf16.h>
#include <cstdint>

// ---------------------------------------------------------------------------
// BaseAttention: GQA fwd, b=1 S=4096 d=2048, 32 Q / 8 KV heads, HD=64, causal.
// fp32 in/out; bf16 intermediates.
//
// Round 16 (= Round 15 + XCD-chunk swizzles + setprio on attn MFMA):
//  - Attn: blocks re-indexed so XCD k owns KV-group g=k (bflat%8 chunk,
//    512%8==0 bijective). K+V per group = 1 MB -> resident in that XCD's
//    4 MiB L2 (was: every XCD cycling all 8 groups = 8 MB, thrashing).
//    R15 FETCH 54 MB vs 24 MB ideal is this miss traffic.
//    s_setprio(1) around QK- and PV-MFMA clusters (T5; attn-positive).
//  - Both GEMMs: T1 chunk swizzle (768/512 % 8 == 0) -> each XCD walks 4
//    consecutive A-row panels (A-panel L2 reuse) instead of scattered.
//  - Attn pipeline unchanged from R15 (KVBLK=128, 1 barrier/128 keys).
//  - GEMMs (2-phase double-buffered) + casts unchanged.
// ---------------------------------------------------------------------------

typedef unsigned int u32;
typedef unsigned short u16;
typedef __attribute__((ext_vector_type(8))) short bf16x8;
typedef __attribute__((ext_vector_type(4))) float f32x4;
typedef __attribute__((ext_vector_type(2))) u32 u32x2;

typedef __attribute__((address_space(3))) void lds_void_t;
typedef __attribute__((address_space(1))) void gbl_void_t;

__device__ __forceinline__ void gload_lds16(const u16* g, u16* l) {
    __builtin_amdgcn_global_load_lds((const gbl_void_t*)g, (lds_void_t*)l, 16, 0, 0);
}

__device__ __forceinline__ u16 f2bf(float f) {
    union { float f; u32 i; } c; c.f = f;
    return (u16)((c.i + 0x7fffu + ((c.i >> 16) & 1u)) >> 16);
}
__device__ __forceinline__ float bfround(float f) {
    union { float f; u32 i; } c; c.f = f;
    c.i = (c.i + 0x7fffu + ((c.i >> 16) & 1u)) & 0xffff0000u;
    return c.f;
}
__device__ __forceinline__ u32 packbf2(float a, float b) {  // v_cvt_pk_bf16_f32
    union { __hip_bfloat162 h; u32 w; } c;
    c.h = __float22bfloat162_rn(make_float2(a, b));
    return c.w;   // a in low 16, b in high 16
}

// ---------------------------------------------------------------------------
// casts
// ---------------------------------------------------------------------------
__global__ __launch_bounds__(256) void cast_f2b_kernel(
    const float* __restrict__ s, u16* __restrict__ d)
{
    int i = (blockIdx.x * 256 + threadIdx.x) * 8;
    float4 a = *reinterpret_cast<const float4*>(s + i);
    float4 b = *reinterpret_cast<const float4*>(s + i + 4);
    u32 w[4];
    w[0] = packbf2(a.x, a.y); w[1] = packbf2(a.z, a.w);
    w[2] = packbf2(b.x, b.y); w[3] = packbf2(b.z, b.w);
    *reinterpret_cast<uint4*>(d + i) = *reinterpret_cast<const uint4*>(w);
}

__global__ __launch_bounds__(256) void cast_transpose_kernel(
    const float* __restrict__ W, u16* __restrict__ Wt, int K, int N)
{
    __shared__ float tile[64][65];
    const int k0 = blockIdx.y * 64, n0 = blockIdx.x * 64;
    const int t = threadIdx.x;
#pragma unroll
    for (int i = 0; i < 16; ++i) {
        int idx = t + i * 256;
        int r = idx >> 6, c = idx & 63;
        tile[r][c] = W[(size_t)(k0 + r) * N + n0 + c];
    }
    __syncthreads();
#pragma unroll
    for (int i = 0; i < 16; ++i) {
        int idx = t + i * 256;
        int r = idx >> 6, c = idx & 63;
        Wt[(size_t)(n0 + r) * K + k0 + c] = f2bf(tile[c][r]);
    }
}

// ---------------------------------------------------------------------------
// Fused QKV MFMA GEMM, double-buffered 2-phase staging, XCD chunk swizzle.
// A = xb[4096][2048], Bt = Wqkvt[3072][2048]
// (rows 0..2047 = Wq^T, 2048..2559 = Wk^T, 2560..3071 = Wv^T).
// Column tile routes: Q (bf16, scaled) / K (bf16) / V (bf16 transposed).
// ---------------------------------------------------------------------------
__global__ __launch_bounds__(256) void gemm_qkv_kernel(
    const u16* __restrict__ A, const u16* __restrict__ Bt,
    u16* __restrict__ Qw, u16* __restrict__ Kw, u16* __restrict__ Vtw,
    int M, int K, float qscale)
{
    __shared__ __align__(16) u16 As[2][128][32];
    __shared__ __align__(16) u16 Bs[2][128][32];

    const int tid  = threadIdx.x;
    const int wave = tid >> 6;
    const int lane = tid & 63;
    const int col  = lane & 15;
    const int quad = lane >> 4;
    // XCD chunk swizzle: 768 blocks, 96 per XCD (4 A-row panels x 24 cols)
    const int bflat = (int)blockIdx.y * 24 + (int)blockIdx.x;
    const int nb_   = (bflat & 7) * 96 + (bflat >> 3);
    const int bm = (nb_ / 24) * 128, bn = (nb_ % 24) * 128;
    const int mhalf = (wave & 1) * 64, nhalf = (wave >> 1) * 64;

    const int srow = wave * 32 + (lane >> 2);
    const int skch = lane & 3;
    const u16* ga = A  + (size_t)(bm + srow) * K + skch * 8;
    const u16* gb = Bt + (size_t)(bn + srow) * K + skch * 8;
    const int w32 = wave * 32;

    f32x4 acc[4][4];
#pragma unroll
    for (int i = 0; i < 4; ++i)
#pragma unroll
        for (int j = 0; j < 4; ++j) acc[i][j] = (f32x4){0.f, 0.f, 0.f, 0.f};

    // prologue: stage tile 0 into buffer 0
    gload_lds16(ga, &As[0][w32][0]);
    gload_lds16(ga + 16 * K, &As[0][w32 + 16][0]);
    gload_lds16(gb, &Bs[0][w32][0]);
    gload_lds16(gb + 16 * K, &Bs[0][w32 + 16][0]);
    ga += 32; gb += 32;

    for (int k0 = 0; k0 < K; k0 += 32) {
        const int cur = (k0 >> 5) & 1;
        __syncthreads();   // drains DMA into buf[cur]; fences buf[cur^1] reuse

        if (k0 + 32 < K) {  // prefetch next K-tile into the other buffer
            const int nb = cur ^ 1;
            gload_lds16(ga, &As[nb][w32][0]);
            gload_lds16(ga + 16 * K, &As[nb][w32 + 16][0]);
            gload_lds16(gb, &Bs[nb][w32][0]);
            gload_lds16(gb + 16 * K, &Bs[nb][w32 + 16][0]);
            ga += 32; gb += 32;
        }

        bf16x8 af[4], bf[4];
#pragma unroll
        for (int t = 0; t < 4; ++t)
            af[t] = *reinterpret_cast<const bf16x8*>(&As[cur][mhalf + t * 16 + col][quad * 8]);
#pragma unroll
        for (int t = 0; t < 4; ++t)
            bf[t] = *reinterpret_cast<const bf16x8*>(&Bs[cur][nhalf + t * 16 + col][quad * 8]);
#pragma unroll
        for (int tm = 0; tm < 4; ++tm)
#pragma unroll
            for (int tn = 0; tn < 4; ++tn)
                acc[tm][tn] = __builtin_amdgcn_mfma_f32_16x16x32_bf16(
                    af[tm], bf[tn], acc[tm][tn], 0, 0, 0);
    }

    if (bn < 2048) {            // ---- Q route (scaled, row-major [M][2048])
#pragma unroll
        for (int tm = 0; tm < 4; ++tm) {
            int row0 = bm + mhalf + tm * 16 + quad * 4;
#pragma unroll
            for (int r = 0; r < 4; ++r) {
                u16* cp = Qw + (size_t)(row0 + r) * 2048 + bn + nhalf + col;
#pragma unroll
                for (int tn = 0; tn < 4; ++tn)
                    cp[tn * 16] = f2bf(acc[tm][tn][r] * qscale);
            }
        }
    } else if (bn < 2560) {     // ---- K route (row-major [M][512])
        const int cb = bn - 2048;
#pragma unroll
        for (int tm = 0; tm < 4; ++tm) {
            int row0 = bm + mhalf + tm * 16 + quad * 4;
#pragma unroll
            for (int r = 0; r < 4; ++r) {
                u16* cp = Kw + (size_t)(row0 + r) * 512 + cb + nhalf + col;
#pragma unroll
                for (int tn = 0; tn < 4; ++tn)
                    cp[tn * 16] = f2bf(acc[tm][tn][r]);
            }
        }
    } else {                    // ---- V route (transposed [512][M])
        const int cb = bn - 2560;
#pragma unroll
        for (int tn = 0; tn < 4; ++tn) {
            int nrow = cb + nhalf + tn * 16 + col;
#pragma unroll
            for (int tm = 0; tm < 4; ++tm) {
                int m0 = bm + mhalf + tm * 16 + quad * 4;
                ushort4 v;
                v.x = f2bf(acc[tm][tn][0]); v.y = f2bf(acc[tm][tn][1]);
                v.z = f2bf(acc[tm][tn][2]); v.w = f2bf(acc[tm][tn][3]);
                *reinterpret_cast<ushort4*>(&Vtw[(size_t)nrow * M + m0]) = v;
            }
        }
    }
}

// ---------------------------------------------------------------------------
// Out-projection MFMA GEMM, double-buffered 2-phase staging, XCD swizzle.
// fp32 output + bias (bf16-rounded values).
// ---------------------------------------------------------------------------
__global__ __launch_bounds__(256) void gemm_out_kernel(
    const u16* __restrict__ A, const u16* __restrict__ Bt,
    const float* __restrict__ bias, float* __restrict__ Co,
    int M, int N, int K)
{
    __shared__ __align__(16) u16 As[2][128][32];
    __shared__ __align__(16) u16 Bs[2][128][32];

    const int tid  = threadIdx.x;
    const int wave = tid >> 6;
    const int lane = tid & 63;
    const int col  = lane & 15;
    const int quad = lane >> 4;
    // XCD chunk swizzle: 512 blocks, 64 per XCD (4 A-row panels x 16 cols)
    const int bflat = (int)blockIdx.y * 16 + (int)blockIdx.x;
    const int nb_   = (bflat & 7) * 64 + (bflat >> 3);
    const int bm = (nb_ / 16) * 128, bn = (nb_ % 16) * 128;
    const int mhalf = (wave & 1) * 64, nhalf = (wave >> 1) * 64;

    const int srow = wave * 32 + (lane >> 2);
    const int skch = lane & 3;
    const u16* ga = A  + (size_t)(bm + srow) * K + skch * 8;
    const u16* gb = Bt + (size_t)(bn + srow) * K + skch * 8;
    const int w32 = wave * 32;

    f32x4 acc[4][4];
#pragma unroll
    for (int i = 0; i < 4; ++i)
#pragma unroll
        for (int j = 0; j < 4; ++j) acc[i][j] = (f32x4){0.f, 0.f, 0.f, 0.f};

    // prologue: stage tile 0 into buffer 0
    gload_lds16(ga, &As[0][w32][0]);
    gload_lds16(ga + 16 * K, &As[0][w32 + 16][0]);
    gload_lds16(gb, &Bs[0][w32][0]);
    gload_lds16(gb + 16 * K, &Bs[0][w32 + 16][0]);
    ga += 32; gb += 32;

    for (int k0 = 0; k0 < K; k0 += 32) {
        const int cur = (k0 >> 5) & 1;
        __syncthreads();   // drains DMA into buf[cur]; fences buf[cur^1] reuse

        if (k0 + 32 < K) {  // prefetch next K-tile into the other buffer
            const int nb = cur ^ 1;
            gload_lds16(ga, &As[nb][w32][0]);
            gload_lds16(ga + 16 * K, &As[nb][w32 + 16][0]);
            gload_lds16(gb, &Bs[nb][w32][0]);
            gload_lds16(gb + 16 * K, &Bs[nb][w32 + 16][0]);
            ga += 32; gb += 32;
        }

        bf16x8 af[4], bf[4];
#pragma unroll
        for (int t = 0; t < 4; ++t)
            af[t] = *reinterpret_cast<const bf16x8*>(&As[cur][mhalf + t * 16 + col][quad * 8]);
#pragma unroll
        for (int t = 0; t < 4; ++t)
            bf[t] = *reinterpret_cast<const bf16x8*>(&Bs[cur][nhalf + t * 16 + col][quad * 8]);
#pragma unroll
        for (int tm = 0; tm < 4; ++tm)
#pragma unroll
            for (int tn = 0; tn < 4; ++tn)
                acc[tm][tn] = __builtin_amdgcn_mfma_f32_16x16x32_bf16(
                    af[tm], bf[tn], acc[tm][tn], 0, 0, 0);
    }

    float bj[4];
#pragma unroll
    for (int tn = 0; tn < 4; ++tn) bj[tn] = bias[bn + nhalf + tn * 16 + col];
#pragma unroll
    for (int tm = 0; tm < 4; ++tm) {
        int row0 = bm + mhalf + tm * 16 + quad * 4;
#pragma unroll
        for (int r = 0; r < 4; ++r) {
            float* cp = Co + (size_t)(row0 + r) * N + bn + nhalf + col;
#pragma unroll
            for (int tn = 0; tn < 4; ++tn)
                cp[tn * 16] = bfround(acc[tm][tn][r] + bj[tn]);
        }
    }
}

// ---------------------------------------------------------------------------
// Flash attention, fixed-offset softmax, double-buffered K/V staging with
// KVBLK=128 (1 barrier per 128 keys), SWAPPED QK^T (mfma(K,Q)), word-granular
// P repack via Pu, acc init -16 folds softmax offset. Per 128-key tile the
// 64-key body runs twice (h64 halves). t-outer shared K/V fragment reads.
// XCD swizzle: XCD k owns KV-group g=k (K/V 1 MB resident in its L2).
// setprio(1) around QK/PV MFMA clusters (T5).
// Causal balance: block = q-tile pair (31-p heavy, then p): 34 tiles/block.
// Ks[2][128][64] (key-major), Vs[2][64][128] (d-major), Pu[4][1024]: 80 KiB.
// ---------------------------------------------------------------------------
__global__ __launch_bounds__(256, 2) void attn_mfma_kernel(
    const u16* __restrict__ Q,
    const u16* __restrict__ Kd,
    const u16* __restrict__ Vt,
    u16* __restrict__ CTX,
    int S)
{
    __shared__ __align__(16) u16 Ks[2][128][64];
    __shared__ __align__(16) u16 Vs[2][64][128];
    __shared__ __align__(16) u32 Pu[4][1024];

    // XCD chunk swizzle: 512 blocks; XCD k gets nb in [64k, 64k+64) ->
    // h in [4k, 4k+4) -> g = k. (bijective since 512 % 8 == 0)
    const int bflat = (int)blockIdx.y * 16 + (int)blockIdx.x;
    const int nbw   = (bflat & 7) * 64 + (bflat >> 3);
    const int h     = nbw >> 4;            // 0..31
    const int pairi = nbw & 15;            // 0..15
    const int g    = h >> 2;
    const int tid  = threadIdx.x;
    const int wave = tid >> 6;
    const int lane = tid & 63;
    const int col  = lane & 15;
    const int quad = lane >> 4;

    // K staging: lane covers key-row (wave*32 + j*8 + srow8), dim-chunk
    // schk (XOR by row&7 == srow8). 4 gloads/wave per 128-key tile.
    const int srow8 = lane >> 3;
    const int schk  = (lane & 7) ^ srow8;
    const u16* gK = Kd + (size_t)(wave * 32 + srow8) * 512 + g * 64 + schk * 8;

    // V staging: Vs[d][128 keys]; lane covers d-row (wave*16 + j*4 + vrow),
    // key-half vhalf, key-chunk XOR by true row&7: (j*4+vrow)&7 = vrow^(4*(j&1))
    // -> two base pointers (gV0 even j, gV1 odd j).
    const int vrow  = lane >> 4;          // 0..3
    const int vhalf = (lane >> 3) & 1;
    const int vchk0 = (lane & 7) ^ vrow;
    const u16* gVbase = Vt + (size_t)(g * 64 + wave * 16 + vrow) * 4096 + vhalf * 64;
    const u16* gV0 = gVbase + vchk0 * 8;
    const u16* gV1 = gVbase + (vchk0 ^ 4) * 8;

    // Pu word index for packed-P writes (per t: +128 words; per mt: +512)
    const int wbase = ((quad >> 1) * 16 + col) * 4 + (quad & 1) * 2;

#pragma unroll 1
    for (int pass = 0; pass < 2; ++pass) {
        const int qt = pass ? pairi : (31 - pairi);   // heavy pass first
        const int qb = qt * 128;

        bf16x8 qf[2][2];
#pragma unroll
        for (int mt = 0; mt < 2; ++mt) {
            const u16* qp = Q + (size_t)(qb + wave * 32 + mt * 16 + col) * 2048
                            + h * 64 + quad * 8;
            qf[mt][0] = *reinterpret_cast<const bf16x8*>(qp);
            qf[mt][1] = *reinterpret_cast<const bf16x8*>(qp + 32);
        }

        f32x4 o_acc[2][4];
        float l_acc[2];
#pragma unroll
        for (int mt = 0; mt < 2; ++mt) {
            l_acc[mt] = 0.f;
#pragma unroll
            for (int t = 0; t < 4; ++t)
                o_acc[mt][t] = (f32x4){0.f, 0.f, 0.f, 0.f};
        }

        const int ktmax = qt;   // tiles of 128 keys: 0..qt

        // fence prior-pass buf readers, then stage tile 0 into buffer 0
        __syncthreads();
#pragma unroll
        for (int j = 0; j < 4; ++j) {
            gload_lds16(gK + (size_t)(j * 8) * 512, &Ks[0][wave * 32 + j * 8][0]);
            const u16* gv = (j & 1) ? gV1 : gV0;
            gload_lds16(gv + (size_t)(j * 4) * 4096, &Vs[0][wave * 16 + j * 4][0]);
        }

        for (int kt = 0; kt <= ktmax; ++kt) {
            const int cur = kt & 1;
            __syncthreads();   // drains DMA into buf[cur]; fences buf[cur^1] reuse

            if (kt < ktmax) {  // prefetch kt+1 into the other buffer
                const int nb = cur ^ 1;
                const size_t ko = (size_t)(kt + 1) * 128;
#pragma unroll
                for (int j = 0; j < 4; ++j) {
                    gload_lds16(gK + (ko + j * 8) * 512, &Ks[nb][wave * 32 + j * 8][0]);
                    const u16* gv = (j & 1) ? gV1 : gV0;
                    gload_lds16(gv + ko + (size_t)(j * 4) * 4096, &Vs[nb][wave * 16 + j * 4][0]);
                }
            }

            const int base0 = qb + wave * 32;       // mt=0 row base

#pragma unroll
            for (int h64 = 0; h64 < 2; ++h64) {
                const int kbase = kt * 128 + h64 * 64;
                if (kbase > base0 + 31) continue;       // both mt masked
                const bool act0 = (kbase <= base0 + 15);
                const int rbase = h64 * 64;

                // ---- QK phase (t outer; K frags read once, feed both mt) ----
                f32x4 sc0[4], sc1[4];
                __builtin_amdgcn_s_setprio(1);
#pragma unroll
                for (int t = 0; t < 4; ++t) {
                    const int krow = t * 16 + col;
                    bf16x8 k0 = *reinterpret_cast<const bf16x8*>(
                        &Ks[cur][rbase + krow][((quad    ) ^ (krow & 7)) * 8]);
                    bf16x8 k1 = *reinterpret_cast<const bf16x8*>(
                        &Ks[cur][rbase + krow][((quad + 4) ^ (krow & 7)) * 8]);
                    f32x4 c4 = {-16.f, -16.f, -16.f, -16.f};
                    c4 = __builtin_amdgcn_mfma_f32_16x16x32_bf16(k0, qf[1][0], c4, 0, 0, 0);
                    c4 = __builtin_amdgcn_mfma_f32_16x16x32_bf16(k1, qf[1][1], c4, 0, 0, 0);
                    sc1[t] = c4;
                    if (act0) {
                        f32x4 d4 = {-16.f, -16.f, -16.f, -16.f};
                        d4 = __builtin_amdgcn_mfma_f32_16x16x32_bf16(k0, qf[0][0], d4, 0, 0, 0);
                        d4 = __builtin_amdgcn_mfma_f32_16x16x32_bf16(k1, qf[0][1], d4, 0, 0, 0);
                        sc0[t] = d4;
                    }
                }
                __builtin_amdgcn_s_setprio(0);

                // ---- causal mask (qrow(mt) = base0 + mt*16 + col) ----
                if (kbase + 63 > base0) {
#pragma unroll
                    for (int t = 0; t < 4; ++t) {
                        const int keyq = kbase + t * 16 + quad * 4;
#pragma unroll
                        for (int r = 0; r < 4; ++r) {
                            if (keyq + r > base0 + 16 + col) sc1[t][r] = -1e30f;
                            if (act0 && (keyq + r > base0 + col)) sc0[t][r] = -1e30f;
                        }
                    }
                }

                // ---- p = exp2(sc); pack both mt into PV A-fragment words ----
                {
                    float ls0 = 0.f, ls1 = 0.f;
#pragma unroll
                    for (int t = 0; t < 4; ++t) {
                        float p0 = __builtin_amdgcn_exp2f(sc1[t][0]);
                        float p1 = __builtin_amdgcn_exp2f(sc1[t][1]);
                        float p2 = __builtin_amdgcn_exp2f(sc1[t][2]);
                        float p3 = __builtin_amdgcn_exp2f(sc1[t][3]);
                        ls1 += (p0 + p1) + (p2 + p3);
                        u32x2 w;
                        w.x = packbf2(p0, p1);
                        w.y = packbf2(p2, p3);
                        *reinterpret_cast<u32x2*>(&Pu[wave][512 + wbase + t * 128]) = w;
                        if (act0) {
                            float q0 = __builtin_amdgcn_exp2f(sc0[t][0]);
                            float q1 = __builtin_amdgcn_exp2f(sc0[t][1]);
                            float q2 = __builtin_amdgcn_exp2f(sc0[t][2]);
                            float q3 = __builtin_amdgcn_exp2f(sc0[t][3]);
                            ls0 += (q0 + q1) + (q2 + q3);
                            u32x2 v;
                            v.x = packbf2(q0, q1);
                            v.y = packbf2(q2, q3);
                            *reinterpret_cast<u32x2*>(&Pu[wave][wbase + t * 128]) = v;
                        }
                    }
                    l_acc[1] += ls1;
                    if (act0) l_acc[0] += ls0;
                }

                // drain LDS writes only (lgkmcnt(0); vmcnt=63 keeps DMA going)
                __builtin_amdgcn_s_waitcnt(0xC07F);
                __builtin_amdgcn_wave_barrier();

                bf16x8 pa1_0 = *reinterpret_cast<const bf16x8*>(&Pu[wave][512 + lane * 4]);
                bf16x8 pa1_1 = *reinterpret_cast<const bf16x8*>(&Pu[wave][768 + lane * 4]);
                bf16x8 pa0_0, pa0_1;
                if (act0) {
                    pa0_0 = *reinterpret_cast<const bf16x8*>(&Pu[wave][lane * 4]);
                    pa0_1 = *reinterpret_cast<const bf16x8*>(&Pu[wave][256 + lane * 4]);
                }

                // ---- PV phase (t outer; V frags read once, feed both mt) ----
                __builtin_amdgcn_s_setprio(1);
#pragma unroll
                for (int t = 0; t < 4; ++t) {
                    const int d = t * 16 + col;
                    bf16x8 vb0 = *reinterpret_cast<const bf16x8*>(
                        &Vs[cur][d][rbase + ((quad    ) ^ (d & 7)) * 8]);
                    bf16x8 vb1 = *reinterpret_cast<const bf16x8*>(
                        &Vs[cur][d][rbase + ((quad + 4) ^ (d & 7)) * 8]);
                    o_acc[1][t] = __builtin_amdgcn_mfma_f32_16x16x32_bf16(pa1_0, vb0, o_acc[1][t], 0, 0, 0);
                    o_acc[1][t] = __builtin_amdgcn_mfma_f32_16x16x32_bf16(pa1_1, vb1, o_acc[1][t], 0, 0, 0);
                    if (act0) {
                        o_acc[0][t] = __builtin_amdgcn_mfma_f32_16x16x32_bf16(pa0_0, vb0, o_acc[0][t], 0, 0, 0);
                        o_acc[0][t] = __builtin_amdgcn_mfma_f32_16x16x32_bf16(pa0_1, vb1, o_acc[0][t], 0, 0, 0);
                    }
                }
                __builtin_amdgcn_s_setprio(0);
            }
        }

        // ---- epilogue (per pass) ----
#pragma unroll
        for (int mt = 0; mt < 2; ++mt) {
            // full row-sum for qrow=col lives split across quads: reduce
            float v = l_acc[mt];
            v += __shfl_xor(v, 16, 64);
            v += __shfl_xor(v, 32, 64);
            // redistribute: lane needs l for qrow = quad*4 + r (o_acc row layout)
            const int src0 = (lane & 48) + ((lane >> 4) & 3) * 4;
#pragma unroll
            for (int r = 0; r < 4; ++r) {
                const float lv = __shfl(v, src0 + r, 64);
                const float inv = 1.f / lv;
                const int row = qb + wave * 32 + mt * 16 + quad * 4 + r;
                u16* cp = CTX + (size_t)row * 2048 + h * 64;
#pragma unroll
                for (int t = 0; t < 4; ++t)
                    cp[t * 16 + col] = f2bf(o_acc[mt][t][r] * inv);
            }
        }
    }
}

// ---------------------------------------------------------------------------
extern "C" void kernel_launch(void* const* d_in, const int* in_sizes, int n_in,
                              void* d_out, int out_size, void* d_ws, size_t ws_size,
                              hipStream_t stream)
{
    const float* x  = (const float*)d_in[0];   // [4096, 2048]
    const float* Wq = (const float*)d_in[1];   // [2048, 2048]
    const float* Wk = (const float*)d_in[2];   // [2048, 512]
    const float* Wv = (const float*)d_in[3];   // [2048, 512]
    const float* Wo = (const float*)d_in[4];   // [2048, 2048]
    const float* bo = (const float*)d_in[5];   // [2048]
    float* out = (float*)d_out;                // [4096, 2048]

    const int S = 4096, Din = 2048, Dq = 2048, Dkv = 512;
    const float QSCALE = 0.125f * 1.44269504f; // 1/sqrt(64) * log2(e)

    u16* xb  = (u16*)d_ws;                    // [4096][2048]
    u16* Qw  = xb + (size_t)S * Din;          // [4096][2048]
    u16* Kw  = Qw + (size_t)S * Dq;           // [4096][512]
    u16* Vtw = Kw + (size_t)S * Dkv;          // [512][4096]
    u16* Cw   = xb;        // CTX aliases xb (dead after QKV proj)
    u16* Wobt = Qw;        // Wo^T aliases Q (dead after attn)

    // d_out as scratch: fused Wqkv^T bf16 [3072][2048] (12.6 MB <= 33.5 MB)
    u16* Wqkvt = (u16*)d_out;

    dim3 blk(256);
    cast_f2b_kernel<<<dim3((S * Din) / (256 * 8)), blk, 0, stream>>>(x, xb);
    cast_transpose_kernel<<<dim3(Dq  / 64, Din / 64), blk, 0, stream>>>(Wq, Wqkvt, Din, Dq);
    cast_transpose_kernel<<<dim3(Dkv / 64, Din / 64), blk, 0, stream>>>(Wk, Wqkvt + (size_t)2048 * Din, Din, Dkv);
    cast_transpose_kernel<<<dim3(Dkv / 64, Din / 64), blk, 0, stream>>>(Wv, Wqkvt + (size_t)2560 * Din, Din, Dkv);

    gemm_qkv_kernel<<<dim3(3072 / 128, S / 128), blk, 0, stream>>>(
        xb, Wqkvt, Qw, Kw, Vtw, S, Din, QSCALE);

    attn_mfma_kernel<<<dim3(16, 32), blk, 0, stream>>>(Qw, Kw, Vtw, Cw, S);

    cast_transpose_kernel<<<dim3(Dq / 64, Dq / 64), blk, 0, stream>>>(Wo, Wobt, Dq, Dq);
    gemm_out_kernel<<<dim3(Dq / 128, S / 128), blk, 0, stream>>>(Cw, Wobt, bo, out, S, Dq, Dq);
}